// Round 1
// baseline (1791.003 us; speedup 1.0000x reference)
//
#include <hip/hip_runtime.h>
#include <math.h>

#define NT     100000   // total nodes
#define NPT    50000    // nodes per type
#define NPG    50000    // nodes per metapath graph
#define EG     500000   // edges per graph
#define NHD    4        // heads
#define HDD    64       // per-head dim
#define HIDD   64       // hidden dim
#define DD     256      // NH*HD
#define OUTD   64
#define TT     20000    // targets per metapath

// ---------------------------------------------------------------------------
// fc: transformed[type_idx[ty][r]] = features_ty[r] @ fc_W[ty]^T + fc_b[ty]
// fc_W[ty] is (64,256) row-major = [c][k]; we transpose into LDS as [k][c],
// XOR-swizzled to keep both transpose-writes and reads bank-conflict-free.
// ---------------------------------------------------------------------------
__global__ __launch_bounds__(256) void fc_kernel(
    const float* __restrict__ f0, const float* __restrict__ f1,
    const float* __restrict__ fcW, const float* __restrict__ fcb,
    const int* __restrict__ type_idx, float* __restrict__ transformed)
{
    int ty = blockIdx.y;
    const float* feat = ty ? f1 : f0;
    const float* Wsrc = fcW + ty * 64 * 256;
    __shared__ float Wl[128 * 64];        // k-tile of 128, [k][c] swizzled
    __shared__ float Arow[4][4][256];
    int tid = threadIdx.x, wave = tid >> 6, lane = tid & 63;
    int rbase = blockIdx.x * 16 + wave * 4;

    for (int r = 0; r < 4; ++r) {
        int row = rbase + r;
        if (row < NPT)
            *(float4*)&Arow[wave][r][lane * 4] =
                *(const float4*)&feat[(size_t)row * 256 + lane * 4];
    }
    float acc[4] = {0.f, 0.f, 0.f, 0.f};
    for (int kt = 0; kt < 2; ++kt) {
        __syncthreads();
        for (int i = tid; i < 128 * 64; i += 256) {
            int c = i >> 7, k = i & 127;
            Wl[k * 64 + (c ^ (k & 31))] = Wsrc[c * 256 + kt * 128 + k];
        }
        __syncthreads();
        for (int k4 = 0; k4 < 32; ++k4) {
            float w[4];
#pragma unroll
            for (int j = 0; j < 4; ++j) {
                int k = k4 * 4 + j;
                w[j] = Wl[k * 64 + (lane ^ (k & 31))];
            }
#pragma unroll
            for (int r = 0; r < 4; ++r) {
                float4 a = *(const float4*)&Arow[wave][r][kt * 128 + k4 * 4];
                acc[r] += a.x * w[0] + a.y * w[1] + a.z * w[2] + a.w * w[3];
            }
        }
    }
    float bias = fcb[ty * 64 + lane];
    for (int r = 0; r < 4; ++r) {
        int row = rbase + r;
        if (row < NPT) {
            int dest = type_idx[ty * NPT + row];
            transformed[(size_t)dest * 64 + lane] = acc[r] + bias;
        }
    }
}

// ---------------------------------------------------------------------------
// z = transformed[node_idx] @ gat_W   (50000x64 @ 64x256)
// gat_W already [k][c] row-major -> direct LDS copy, conflict-free reads.
// ---------------------------------------------------------------------------
__global__ __launch_bounds__(256) void z_kernel(
    const float* __restrict__ transformed, const int* __restrict__ nidx,
    const float* __restrict__ gatW, float* __restrict__ z)
{
    __shared__ float Wl[32 * 256];        // k-tile of 32
    __shared__ float Arow[4][4][64];
    int tid = threadIdx.x, wave = tid >> 6, lane = tid & 63;
    int rbase = blockIdx.x * 16 + wave * 4;
    for (int r = 0; r < 4; ++r) {
        int row = rbase + r;
        if (row < NPG) {
            int n = nidx[row];
            Arow[wave][r][lane] = transformed[(size_t)n * 64 + lane];
        }
    }
    float acc[4][4] = {};
    for (int kt = 0; kt < 2; ++kt) {
        __syncthreads();
        for (int i = tid; i < 32 * 256; i += 256)
            Wl[i] = gatW[kt * 32 * 256 + i];
        __syncthreads();
        for (int k4 = 0; k4 < 8; ++k4) {
            float w[4][4];
#pragma unroll
            for (int j = 0; j < 4; ++j) {
                int k = k4 * 4 + j;
#pragma unroll
                for (int cc = 0; cc < 4; ++cc)
                    w[j][cc] = Wl[k * 256 + cc * 64 + lane];
            }
#pragma unroll
            for (int r = 0; r < 4; ++r) {
                float4 a = *(const float4*)&Arow[wave][r][kt * 32 + k4 * 4];
#pragma unroll
                for (int cc = 0; cc < 4; ++cc)
                    acc[r][cc] += a.x * w[0][cc] + a.y * w[1][cc]
                                + a.z * w[2][cc] + a.w * w[3][cc];
            }
        }
    }
    for (int r = 0; r < 4; ++r) {
        int row = rbase + r;
        if (row < NPG) {
#pragma unroll
            for (int cc = 0; cc < 4; ++cc)
                z[(size_t)row * 256 + cc * 64 + lane] = acc[r][cc];
        }
    }
}

// ---------------------------------------------------------------------------
// el/er: per node n, head h:  el[n][h] = sum_hd z[n][h*64+hd]*attn_l[h][hd]
// one wave per row; lane covers 4 contiguous z elements -> b128 coalesced.
// ---------------------------------------------------------------------------
__global__ __launch_bounds__(256) void elr_kernel(
    const float* __restrict__ z, const float* __restrict__ al,
    const float* __restrict__ ar, float* __restrict__ el, float* __restrict__ er)
{
    int gid = blockIdx.x * 256 + threadIdx.x;
    int row = gid >> 6;
    int lane = threadIdx.x & 63;
    if (row >= NPG) return;
    int head = lane >> 4;
    int hd0 = (lane & 15) * 4;
    float4 zv = *(const float4*)&z[(size_t)row * 256 + lane * 4];
    float4 alv = *(const float4*)&al[head * 64 + hd0];
    float4 arv = *(const float4*)&ar[head * 64 + hd0];
    float pl = zv.x * alv.x + zv.y * alv.y + zv.z * alv.z + zv.w * alv.w;
    float pr = zv.x * arv.x + zv.y * arv.y + zv.z * arv.z + zv.w * arv.w;
    for (int o = 1; o < 16; o <<= 1) {
        pl += __shfl_xor(pl, o);
        pr += __shfl_xor(pr, o);
    }
    if ((lane & 15) == 0) {
        el[row * 4 + head] = pl;
        er[row * 4 + head] = pr;
    }
}

// ---------------------------------------------------------------------------
// CSR build: count -> scan -> scatter (perm stores SRC node directly)
// ---------------------------------------------------------------------------
__global__ void count_kernel(const int* __restrict__ dst, int* __restrict__ deg)
{
    int e = blockIdx.x * 256 + threadIdx.x;
    if (e < EG) atomicAdd(&deg[dst[e]], 1);
}

__global__ __launch_bounds__(1024) void scan_kernel(
    const int* __restrict__ deg, int* __restrict__ offsets, int* __restrict__ cursor)
{
    __shared__ int part[1024];
    int t = threadIdx.x;
    int i0 = t * 49;
    int i1 = min(i0 + 49, NPG);
    int s = 0;
    for (int i = i0; i < i1; ++i) s += deg[i];
    part[t] = s;
    __syncthreads();
    for (int d = 1; d < 1024; d <<= 1) {
        int v = (t >= d) ? part[t - d] : 0;
        __syncthreads();
        part[t] += v;
        __syncthreads();
    }
    int run = part[t] - s;   // exclusive prefix
    for (int i = i0; i < i1; ++i) {
        offsets[i] = run;
        cursor[i] = run;
        run += deg[i];
    }
    if (t == 1023) offsets[NPG] = part[1023];
}

__global__ void scatter_kernel(const int* __restrict__ dst,
                               const int* __restrict__ src,
                               int* __restrict__ cursor, int* __restrict__ perm)
{
    int e = blockIdx.x * 256 + threadIdx.x;
    if (e < EG) {
        int d = dst[e];
        int pos = atomicAdd(&cursor[d], 1);
        perm[pos] = src[e];   // store src node directly
    }
}

// ---------------------------------------------------------------------------
// Aggregation: one block per target t, one wave per head. Two-pass online
// softmax over the dst node's in-edges; lane covers one of 64 head dims.
// Writes meta[t][h*64+lane] = elu(sum(ex*z[src]) / (denom+1e-9))
// ---------------------------------------------------------------------------
__global__ __launch_bounds__(256) void agg_kernel(
    const int* __restrict__ tgt, const int* __restrict__ offsets,
    const int* __restrict__ perm, const float* __restrict__ el,
    const float* __restrict__ er, const float* __restrict__ z,
    float* __restrict__ meta)
{
    int t = blockIdx.x;
    int h = threadIdx.x >> 6;
    int lane = threadIdx.x & 63;
    int dstn = tgt[t];
    int start = offsets[dstn], end = offsets[dstn + 1];
    float erv = er[dstn * 4 + h];
    // pass 1: max over edges (lane-parallel)
    float mx = -INFINITY;
    for (int i = start + lane; i < end; i += 64) {
        int s = perm[i];
        float v = el[s * 4 + h] + erv;
        v = v > 0.f ? v : 0.2f * v;
        mx = fmaxf(mx, v);
    }
    for (int o = 32; o > 0; o >>= 1) mx = fmaxf(mx, __shfl_xor(mx, o));
    // pass 2: denom + weighted sum (uniform loop, coalesced z reads)
    float acc = 0.f, denom = 0.f;
    for (int i = start; i < end; ++i) {
        int s = perm[i];
        float v = el[s * 4 + h] + erv;
        v = v > 0.f ? v : 0.2f * v;
        float ex = __expf(v - mx);
        denom += ex;
        acc += ex * z[(size_t)s * 256 + h * 64 + lane];
    }
    float o = acc / (denom + 1e-9f);
    o = o > 0.f ? o : expm1f(o);
    meta[(size_t)t * 256 + h * 64 + lane] = o;
}

// ---------------------------------------------------------------------------
// Semantic attention logits: wsum[m] += sum_t tanh(meta[m][t]@W + b) @ q
// ---------------------------------------------------------------------------
__global__ __launch_bounds__(256) void sem_kernel(
    const float* __restrict__ metas, const float* __restrict__ semW,
    const float* __restrict__ semb, const float* __restrict__ semq,
    float* __restrict__ wsum)
{
    int m = blockIdx.y;
    const float* A = metas + (size_t)m * TT * 256;
    __shared__ float Wt[32 * 256];
    __shared__ float Arow[4][4][256];
    __shared__ float bsum;
    int tid = threadIdx.x, wave = tid >> 6, lane = tid & 63;
    if (tid == 0) bsum = 0.f;
    int rbase = blockIdx.x * 16 + wave * 4;
    for (int r = 0; r < 4; ++r)
        *(float4*)&Arow[wave][r][lane * 4] =
            *(const float4*)&A[(size_t)(rbase + r) * 256 + lane * 4];
    float acc[4][4] = {};
    for (int kt = 0; kt < 8; ++kt) {
        __syncthreads();
        for (int i = tid; i < 32 * 256; i += 256)
            Wt[i] = semW[kt * 32 * 256 + i];
        __syncthreads();
        for (int k4 = 0; k4 < 8; ++k4) {
            float w[4][4];
#pragma unroll
            for (int j = 0; j < 4; ++j) {
                int k = k4 * 4 + j;
#pragma unroll
                for (int cc = 0; cc < 4; ++cc)
                    w[j][cc] = Wt[k * 256 + cc * 64 + lane];
            }
#pragma unroll
            for (int r = 0; r < 4; ++r) {
                float4 a = *(const float4*)&Arow[wave][r][kt * 32 + k4 * 4];
#pragma unroll
                for (int cc = 0; cc < 4; ++cc)
                    acc[r][cc] += a.x * w[0][cc] + a.y * w[1][cc]
                                + a.z * w[2][cc] + a.w * w[3][cc];
            }
        }
    }
    float rowsum = 0.f;
#pragma unroll
    for (int r = 0; r < 4; ++r) {
        float p = 0.f;
#pragma unroll
        for (int cc = 0; cc < 4; ++cc) {
            int col = cc * 64 + lane;
            p += tanhf(acc[r][cc] + semb[col]) * semq[col];
        }
        rowsum += p;
    }
    for (int o = 32; o > 0; o >>= 1) rowsum += __shfl_xor(rowsum, o);
    if (lane == 0) atomicAdd(&bsum, rowsum);
    __syncthreads();
    if (tid == 0) atomicAdd(&wsum[m], bsum);
}

// ---------------------------------------------------------------------------
// Output: beta = softmax(wsum/T); s = b0*meta0 + b1*meta1; out = s@foW + fob
// ---------------------------------------------------------------------------
__global__ __launch_bounds__(256) void out_kernel(
    const float* __restrict__ metas, const float* __restrict__ wsum,
    const float* __restrict__ foW, const float* __restrict__ fob,
    float* __restrict__ out)
{
    __shared__ float Wl[128 * 64];
    __shared__ float Srow[4][4][256];
    int tid = threadIdx.x, wave = tid >> 6, lane = tid & 63;
    float w0 = wsum[0] * (1.f / TT), w1 = wsum[1] * (1.f / TT);
    float mxv = fmaxf(w0, w1);
    float e0 = __expf(w0 - mxv), e1 = __expf(w1 - mxv);
    float inv = 1.f / (e0 + e1);
    float b0 = e0 * inv, b1 = e1 * inv;
    int rbase = blockIdx.x * 16 + wave * 4;
    for (int r = 0; r < 4; ++r) {
        int row = rbase + r;
        float4 a = *(const float4*)&metas[(size_t)row * 256 + lane * 4];
        float4 c = *(const float4*)&metas[(size_t)TT * 256 + (size_t)row * 256 + lane * 4];
        float4 s;
        s.x = b0 * a.x + b1 * c.x;
        s.y = b0 * a.y + b1 * c.y;
        s.z = b0 * a.z + b1 * c.z;
        s.w = b0 * a.w + b1 * c.w;
        *(float4*)&Srow[wave][r][lane * 4] = s;
    }
    float acc[4] = {0.f, 0.f, 0.f, 0.f};
    for (int kt = 0; kt < 2; ++kt) {
        __syncthreads();
        for (int i = tid; i < 128 * 64; i += 256)
            Wl[i] = foW[kt * 128 * 64 + i];
        __syncthreads();
        for (int k4 = 0; k4 < 32; ++k4) {
            float w[4];
#pragma unroll
            for (int j = 0; j < 4; ++j) w[j] = Wl[(k4 * 4 + j) * 64 + lane];
#pragma unroll
            for (int r = 0; r < 4; ++r) {
                float4 a = *(const float4*)&Srow[wave][r][kt * 128 + k4 * 4];
                acc[r] += a.x * w[0] + a.y * w[1] + a.z * w[2] + a.w * w[3];
            }
        }
    }
    float bias = fob[lane];
    for (int r = 0; r < 4; ++r)
        out[(size_t)(rbase + r) * 64 + lane] = acc[r] + bias;
}

// ---------------------------------------------------------------------------
extern "C" void kernel_launch(void* const* d_in, const int* in_sizes, int n_in,
                              void* d_out, int out_size, void* d_ws, size_t ws_size,
                              hipStream_t stream)
{
    const float* f0    = (const float*)d_in[0];
    const float* f1    = (const float*)d_in[1];
    const float* fcW   = (const float*)d_in[2];
    const float* fcb   = (const float*)d_in[3];
    const float* gatW  = (const float*)d_in[4];
    const float* al    = (const float*)d_in[5];
    const float* ar    = (const float*)d_in[6];
    const float* semW  = (const float*)d_in[7];
    const float* semb  = (const float*)d_in[8];
    const float* semq  = (const float*)d_in[9];
    const float* foW   = (const float*)d_in[10];
    const float* fob   = (const float*)d_in[11];
    const int* type_idx = (const int*)d_in[12];
    const int* node_idx = (const int*)d_in[13];
    const int* edge_src = (const int*)d_in[14];
    const int* edge_dst = (const int*)d_in[15];
    const int* tgt_idx  = (const int*)d_in[16];
    float* out = (float*)d_out;

    char* ws = (char*)d_ws;
    size_t off = 0;
    auto alloc = [&](size_t bytes) -> void* {
        void* p = ws + off;
        off = (off + bytes + 255) & ~(size_t)255;
        return p;
    };
    float* transformed = (float*)alloc((size_t)NT * 64 * 4);
    float* z           = (float*)alloc((size_t)NPG * 256 * 4);
    float* el          = (float*)alloc((size_t)NPG * 4 * 4);
    float* er          = (float*)alloc((size_t)NPG * 4 * 4);
    float* metas       = (float*)alloc((size_t)2 * TT * 256 * 4);
    float* wsum        = (float*)alloc(64);
    int*   deg         = (int*)alloc((size_t)NPG * 4);
    int*   offsets     = (int*)alloc((size_t)(NPG + 1) * 4);
    int*   cursor      = (int*)alloc((size_t)NPG * 4);
    int*   perm        = (int*)alloc((size_t)EG * 4);

    fc_kernel<<<dim3(3125, 2), 256, 0, stream>>>(f0, f1, fcW, fcb, type_idx,
                                                 transformed);
    const int eblocks = (EG + 255) / 256;
    for (int b = 0; b < 2; ++b) {
        for (int m = 0; m < 2; ++m) {
            int g = b * 2 + m;
            hipMemsetAsync(deg, 0, (size_t)NPG * 4, stream);
            count_kernel<<<eblocks, 256, 0, stream>>>(edge_dst + (size_t)g * EG, deg);
            scan_kernel<<<1, 1024, 0, stream>>>(deg, offsets, cursor);
            scatter_kernel<<<eblocks, 256, 0, stream>>>(
                edge_dst + (size_t)g * EG, edge_src + (size_t)g * EG, cursor, perm);
            z_kernel<<<3125, 256, 0, stream>>>(
                transformed, node_idx + (size_t)g * NPG, gatW + (size_t)g * 64 * 256, z);
            elr_kernel<<<12500, 256, 0, stream>>>(
                z, al + (size_t)g * 256, ar + (size_t)g * 256, el, er);
            agg_kernel<<<TT, 256, 0, stream>>>(
                tgt_idx + (size_t)g * TT, offsets, perm, el, er, z,
                metas + (size_t)m * TT * 256);
        }
        hipMemsetAsync(wsum, 0, 2 * 4, stream);
        sem_kernel<<<dim3(1250, 2), 256, 0, stream>>>(
            metas, semW + (size_t)b * 256 * 256, semb + (size_t)b * 256,
            semq + (size_t)b * 256, wsum);
        out_kernel<<<1250, 256, 0, stream>>>(
            metas, wsum, foW + (size_t)b * 256 * 64, fob + (size_t)b * 64,
            out + (size_t)b * TT * 64);
    }
}

// Round 2
// 1293.949 us; speedup vs baseline: 1.3841x; 1.3841x over previous
//
#include <hip/hip_runtime.h>
#include <math.h>

#define NT     100000   // total nodes
#define NPT    50000    // nodes per type
#define NPG    50000    // nodes per metapath graph
#define EG     500000   // edges per graph
#define DD     256      // NH*HD
#define TT     20000    // targets per metapath

typedef __attribute__((ext_vector_type(8))) short short8;   // 8 bf16 = 4 VGPRs
typedef __attribute__((ext_vector_type(4))) float f32x4;    // MFMA C/D

#define MFMA16(a, b, c) __builtin_amdgcn_mfma_f32_16x16x32_bf16((a), (b), (c), 0, 0, 0)

// RNE float->bf16, packed pair
__device__ inline unsigned pk2(float x, float y) {
    unsigned a = __float_as_uint(x); a = (a + 0x7FFFu + ((a >> 16) & 1u)) >> 16;
    unsigned b = __float_as_uint(y); b = (b + 0x7FFFu + ((b >> 16) & 1u)) >> 16;
    return (a & 0xFFFFu) | (b << 16);
}
__device__ inline int2 pk4(float4 v) {
    int2 r; r.x = (int)pk2(v.x, v.y); r.y = (int)pk2(v.z, v.w); return r;
}

// ---------------------------------------------------------------------------
// fc: transformed[type_idx[ty][r]] = features_ty @ fc_W[ty]^T + fc_b[ty]
// M=50000 (x2 types via blockIdx.y), K=256 (chunked x2), N=64.
// fc_W is [n][k] row-major already — direct convert into Bt LDS.
// LDS row stride = Kchunk+8 bf16 (272 B == 68 words == 4 mod 32 -> 2-way free)
// ---------------------------------------------------------------------------
__global__ __launch_bounds__(256) void fc_kernel(
    const float* __restrict__ f0, const float* __restrict__ f1,
    const float* __restrict__ fcW, const float* __restrict__ fcb,
    const int* __restrict__ type_idx, float* __restrict__ transformed)
{
    __shared__ short As[64 * 136];
    __shared__ short Bs[64 * 136];
    int ty = blockIdx.y;
    const float* feat = ty ? f1 : f0;
    const float* W = fcW + (size_t)ty * 64 * 256;
    int tid = threadIdx.x, wv = tid >> 6, l = tid & 63, q = l >> 4, c = l & 15;
    int rbase = blockIdx.x * 64;
    f32x4 acc[4];
#pragma unroll
    for (int i = 0; i < 4; ++i) acc[i] = (f32x4){0.f, 0.f, 0.f, 0.f};

    for (int kt = 0; kt < 2; ++kt) {
        __syncthreads();
        // stage A chunk (64 rows x 128 k) + B chunk (64 n x 128 k), both [row][k]
#pragma unroll
        for (int j = 0; j < 8; ++j) {
            int e = j * 1024 + tid * 4;
            int r = e >> 7, k = e & 127;
            int2 w = make_int2(0, 0);
            if (rbase + r < NPT)
                w = pk4(*(const float4*)&feat[(size_t)(rbase + r) * 256 + kt * 128 + k]);
            *(int2*)&As[r * 136 + k] = w;
            *(int2*)&Bs[r * 136 + k] =
                pk4(*(const float4*)&W[(size_t)r * 256 + kt * 128 + k]);
        }
        __syncthreads();
        const short* Ap = &As[(wv * 16 + c) * 136 + q * 8];
        short8 af[4];
#pragma unroll
        for (int kk = 0; kk < 4; ++kk) af[kk] = *(const short8*)&Ap[kk * 32];
#pragma unroll
        for (int t4 = 0; t4 < 4; ++t4) {
            const short* Bp = &Bs[(t4 * 16 + c) * 136 + q * 8];
#pragma unroll
            for (int kk = 0; kk < 4; ++kk)
                acc[t4] = MFMA16(af[kk], *(const short8*)&Bp[kk * 32], acc[t4]);
        }
    }
    int grl = rbase + wv * 16 + q * 4;
#pragma unroll
    for (int t4 = 0; t4 < 4; ++t4) {
        int col = t4 * 16 + c;
        float bv = fcb[ty * 64 + col];
#pragma unroll
        for (int reg = 0; reg < 4; ++reg) {
            int gr = grl + reg;
            if (gr < NPT) {
                int dest = type_idx[ty * NPT + gr];
                transformed[(size_t)dest * 64 + col] = acc[t4][reg] + bv;
            }
        }
    }
}

// ---------------------------------------------------------------------------
// z = transformed[node_idx] @ gat_W : M=50000 (gathered rows), K=64, N=256.
// gat_W is [k][n] -> transposed into Bt[n][k] LDS during staging.
// ---------------------------------------------------------------------------
__global__ __launch_bounds__(256) void z_kernel(
    const float* __restrict__ transformed, const int* __restrict__ nidx,
    const float* __restrict__ gatW, float* __restrict__ z)
{
    __shared__ short As[64 * 72];
    __shared__ short Bs[256 * 72];
    int tid = threadIdx.x, wv = tid >> 6, l = tid & 63, q = l >> 4, c = l & 15;
    int rbase = blockIdx.x * 64;
    // A: gather 64 rows of 64 floats
#pragma unroll
    for (int j = 0; j < 4; ++j) {
        int e = j * 1024 + tid * 4;
        int r = e >> 6, k = e & 63;
        int2 w = make_int2(0, 0);
        if (rbase + r < NPG) {
            int n = nidx[rbase + r];
            w = pk4(*(const float4*)&transformed[(size_t)n * 64 + k]);
        }
        *(int2*)&As[r * 72 + k] = w;
    }
    // B: transpose-convert 64x256 -> Bt[256][64]
    {
        int n = tid;
        for (int kp = 0; kp < 32; ++kp) {
            float x = gatW[(size_t)(2 * kp) * 256 + n];
            float y = gatW[(size_t)(2 * kp + 1) * 256 + n];
            *(unsigned*)&Bs[n * 72 + 2 * kp] = pk2(x, y);
        }
    }
    __syncthreads();
    const short* Ap = &As[(wv * 16 + c) * 72 + q * 8];
    short8 a0 = *(const short8*)&Ap[0];
    short8 a1 = *(const short8*)&Ap[32];
    f32x4 acc[16];
    const f32x4 zero = (f32x4){0.f, 0.f, 0.f, 0.f};
#pragma unroll
    for (int t16 = 0; t16 < 16; ++t16) {
        const short* Bp = &Bs[(t16 * 16 + c) * 72 + q * 8];
        acc[t16] = MFMA16(a0, *(const short8*)&Bp[0], zero);
        acc[t16] = MFMA16(a1, *(const short8*)&Bp[32], acc[t16]);
    }
    int grl = rbase + wv * 16 + q * 4;
#pragma unroll
    for (int t16 = 0; t16 < 16; ++t16)
#pragma unroll
        for (int reg = 0; reg < 4; ++reg) {
            int gr = grl + reg;
            if (gr < NPG)
                z[(size_t)gr * 256 + t16 * 16 + c] = acc[t16][reg];
        }
}

// ---------------------------------------------------------------------------
// el/er per node/head (unchanged, fp32)
// ---------------------------------------------------------------------------
__global__ __launch_bounds__(256) void elr_kernel(
    const float* __restrict__ z, const float* __restrict__ al,
    const float* __restrict__ ar, float* __restrict__ el, float* __restrict__ er)
{
    int gid = blockIdx.x * 256 + threadIdx.x;
    int row = gid >> 6;
    int lane = threadIdx.x & 63;
    if (row >= NPG) return;
    int head = lane >> 4;
    int hd0 = (lane & 15) * 4;
    float4 zv = *(const float4*)&z[(size_t)row * 256 + lane * 4];
    float4 alv = *(const float4*)&al[head * 64 + hd0];
    float4 arv = *(const float4*)&ar[head * 64 + hd0];
    float pl = zv.x * alv.x + zv.y * alv.y + zv.z * alv.z + zv.w * alv.w;
    float pr = zv.x * arv.x + zv.y * arv.y + zv.z * arv.z + zv.w * arv.w;
    for (int o = 1; o < 16; o <<= 1) {
        pl += __shfl_xor(pl, o);
        pr += __shfl_xor(pr, o);
    }
    if ((lane & 15) == 0) {
        el[row * 4 + head] = pl;
        er[row * 4 + head] = pr;
    }
}

// ---------------------------------------------------------------------------
// CSR build (unchanged)
// ---------------------------------------------------------------------------
__global__ void count_kernel(const int* __restrict__ dst, int* __restrict__ deg)
{
    int e = blockIdx.x * 256 + threadIdx.x;
    if (e < EG) atomicAdd(&deg[dst[e]], 1);
}

__global__ __launch_bounds__(1024) void scan_kernel(
    const int* __restrict__ deg, int* __restrict__ offsets, int* __restrict__ cursor)
{
    __shared__ int part[1024];
    int t = threadIdx.x;
    int i0 = t * 49;
    int i1 = min(i0 + 49, NPG);
    int s = 0;
    for (int i = i0; i < i1; ++i) s += deg[i];
    part[t] = s;
    __syncthreads();
    for (int d = 1; d < 1024; d <<= 1) {
        int v = (t >= d) ? part[t - d] : 0;
        __syncthreads();
        part[t] += v;
        __syncthreads();
    }
    int run = part[t] - s;
    for (int i = i0; i < i1; ++i) {
        offsets[i] = run;
        cursor[i] = run;
        run += deg[i];
    }
    if (t == 1023) offsets[NPG] = part[1023];
}

__global__ void scatter_kernel(const int* __restrict__ dst,
                               const int* __restrict__ src,
                               int* __restrict__ cursor, int* __restrict__ perm)
{
    int e = blockIdx.x * 256 + threadIdx.x;
    if (e < EG) {
        int d = dst[e];
        int pos = atomicAdd(&cursor[d], 1);
        perm[pos] = src[e];
    }
}

// ---------------------------------------------------------------------------
// Aggregation (unchanged): one block per target, one wave per head.
// ---------------------------------------------------------------------------
__global__ __launch_bounds__(256) void agg_kernel(
    const int* __restrict__ tgt, const int* __restrict__ offsets,
    const int* __restrict__ perm, const float* __restrict__ el,
    const float* __restrict__ er, const float* __restrict__ z,
    float* __restrict__ meta)
{
    int t = blockIdx.x;
    int h = threadIdx.x >> 6;
    int lane = threadIdx.x & 63;
    int dstn = tgt[t];
    int start = offsets[dstn], end = offsets[dstn + 1];
    float erv = er[dstn * 4 + h];
    float mx = -INFINITY;
    for (int i = start + lane; i < end; i += 64) {
        int s = perm[i];
        float v = el[s * 4 + h] + erv;
        v = v > 0.f ? v : 0.2f * v;
        mx = fmaxf(mx, v);
    }
    for (int o = 32; o > 0; o >>= 1) mx = fmaxf(mx, __shfl_xor(mx, o));
    float acc = 0.f, denom = 0.f;
    for (int i = start; i < end; ++i) {
        int s = perm[i];
        float v = el[s * 4 + h] + erv;
        v = v > 0.f ? v : 0.2f * v;
        float ex = __expf(v - mx);
        denom += ex;
        acc += ex * z[(size_t)s * 256 + h * 64 + lane];
    }
    float o = acc / (denom + 1e-9f);
    o = o > 0.f ? o : expm1f(o);
    meta[(size_t)t * 256 + h * 64 + lane] = o;
}

// ---------------------------------------------------------------------------
// Semantic logits: wsum[m] += sum_t tanh(meta[m][t]@W + b)@q
// M=20000, K=256 (chunked x4), N=256. semW [k][n] -> Bt[n][k] per chunk.
// ---------------------------------------------------------------------------
__global__ __launch_bounds__(256) void sem_kernel(
    const float* __restrict__ metas, const float* __restrict__ semW,
    const float* __restrict__ semb, const float* __restrict__ semq,
    float* __restrict__ wsum)
{
    __shared__ short As[64 * 72];
    __shared__ short Bs[256 * 72];
    __shared__ float bsum;
    int m = blockIdx.y;
    const float* A = metas + (size_t)m * TT * 256;
    int tid = threadIdx.x, wv = tid >> 6, l = tid & 63, q = l >> 4, c = l & 15;
    if (tid == 0) bsum = 0.f;
    int rbase = blockIdx.x * 64;
    f32x4 acc[16];
#pragma unroll
    for (int i = 0; i < 16; ++i) acc[i] = (f32x4){0.f, 0.f, 0.f, 0.f};

    for (int kt = 0; kt < 4; ++kt) {
        __syncthreads();
#pragma unroll
        for (int j = 0; j < 4; ++j) {
            int e = j * 1024 + tid * 4;
            int r = e >> 6, k = e & 63;
            int2 w = make_int2(0, 0);
            if (rbase + r < TT)
                w = pk4(*(const float4*)&A[(size_t)(rbase + r) * 256 + kt * 64 + k]);
            *(int2*)&As[r * 72 + k] = w;
        }
        {
            int n = tid;
            for (int kp = 0; kp < 32; ++kp) {
                float x = semW[(size_t)(kt * 64 + 2 * kp) * 256 + n];
                float y = semW[(size_t)(kt * 64 + 2 * kp + 1) * 256 + n];
                *(unsigned*)&Bs[n * 72 + 2 * kp] = pk2(x, y);
            }
        }
        __syncthreads();
        const short* Ap = &As[(wv * 16 + c) * 72 + q * 8];
        short8 a0 = *(const short8*)&Ap[0];
        short8 a1 = *(const short8*)&Ap[32];
#pragma unroll
        for (int t16 = 0; t16 < 16; ++t16) {
            const short* Bp = &Bs[(t16 * 16 + c) * 72 + q * 8];
            acc[t16] = MFMA16(a0, *(const short8*)&Bp[0], acc[t16]);
            acc[t16] = MFMA16(a1, *(const short8*)&Bp[32], acc[t16]);
        }
    }
    float part = 0.f;
    int grl = rbase + wv * 16 + q * 4;
#pragma unroll
    for (int t16 = 0; t16 < 16; ++t16) {
        int col = t16 * 16 + c;
        float bb = semb[col], qq = semq[col];
#pragma unroll
        for (int reg = 0; reg < 4; ++reg)
            if (grl + reg < TT) part += tanhf(acc[t16][reg] + bb) * qq;
    }
    for (int o = 32; o > 0; o >>= 1) part += __shfl_xor(part, o);
    if (l == 0) atomicAdd(&bsum, part);
    __syncthreads();
    if (tid == 0) atomicAdd(&wsum[m], bsum);
}

// ---------------------------------------------------------------------------
// Output: beta = softmax(wsum/T); s = b0*meta0+b1*meta1 (fp32, during staging);
// out = s @ foW + fob. M=20000, K=256 (chunked x2), N=64. foW [k][n] -> Bt.
// ---------------------------------------------------------------------------
__global__ __launch_bounds__(256) void out_kernel(
    const float* __restrict__ metas, const float* __restrict__ wsum,
    const float* __restrict__ foW, const float* __restrict__ fob,
    float* __restrict__ out)
{
    __shared__ short As[64 * 136];
    __shared__ short Bs[64 * 136];
    int tid = threadIdx.x, wv = tid >> 6, l = tid & 63, q = l >> 4, c = l & 15;
    float w0 = wsum[0] * (1.f / TT), w1 = wsum[1] * (1.f / TT);
    float mxv = fmaxf(w0, w1);
    float e0 = __expf(w0 - mxv), e1 = __expf(w1 - mxv);
    float inv = 1.f / (e0 + e1);
    float b0 = e0 * inv, b1 = e1 * inv;
    int rbase = blockIdx.x * 64;
    f32x4 acc[4];
#pragma unroll
    for (int i = 0; i < 4; ++i) acc[i] = (f32x4){0.f, 0.f, 0.f, 0.f};

    for (int kt = 0; kt < 2; ++kt) {
        __syncthreads();
#pragma unroll
        for (int j = 0; j < 8; ++j) {
            int e = j * 1024 + tid * 4;
            int r = e >> 7, k = e & 127;
            int2 w = make_int2(0, 0);
            if (rbase + r < TT) {
                const float* p0 = &metas[(size_t)(rbase + r) * 256 + kt * 128 + k];
                float4 va = *(const float4*)p0;
                float4 vb = *(const float4*)(p0 + (size_t)TT * 256);
                float4 s;
                s.x = b0 * va.x + b1 * vb.x;
                s.y = b0 * va.y + b1 * vb.y;
                s.z = b0 * va.z + b1 * vb.z;
                s.w = b0 * va.w + b1 * vb.w;
                w = pk4(s);
            }
            *(int2*)&As[r * 136 + k] = w;
        }
        {
            int n = tid & 63, kh = tid >> 6;
            for (int kp = 0; kp < 16; ++kp) {
                int k = kh * 32 + 2 * kp;
                float x = foW[(size_t)(kt * 128 + k) * 64 + n];
                float y = foW[(size_t)(kt * 128 + k + 1) * 64 + n];
                *(unsigned*)&Bs[n * 136 + k] = pk2(x, y);
            }
        }
        __syncthreads();
        const short* Ap = &As[(wv * 16 + c) * 136 + q * 8];
        short8 af[4];
#pragma unroll
        for (int kk = 0; kk < 4; ++kk) af[kk] = *(const short8*)&Ap[kk * 32];
#pragma unroll
        for (int t4 = 0; t4 < 4; ++t4) {
            const short* Bp = &Bs[(t4 * 16 + c) * 136 + q * 8];
#pragma unroll
            for (int kk = 0; kk < 4; ++kk)
                acc[t4] = MFMA16(af[kk], *(const short8*)&Bp[kk * 32], acc[t4]);
        }
    }
    int grl = rbase + wv * 16 + q * 4;
#pragma unroll
    for (int t4 = 0; t4 < 4; ++t4) {
        int col = t4 * 16 + c;
        float bv = fob[col];
#pragma unroll
        for (int reg = 0; reg < 4; ++reg) {
            int gr = grl + reg;
            if (gr < TT)
                out[(size_t)gr * 64 + col] = acc[t4][reg] + bv;
        }
    }
}

// ---------------------------------------------------------------------------
extern "C" void kernel_launch(void* const* d_in, const int* in_sizes, int n_in,
                              void* d_out, int out_size, void* d_ws, size_t ws_size,
                              hipStream_t stream)
{
    const float* f0    = (const float*)d_in[0];
    const float* f1    = (const float*)d_in[1];
    const float* fcW   = (const float*)d_in[2];
    const float* fcb   = (const float*)d_in[3];
    const float* gatW  = (const float*)d_in[4];
    const float* al    = (const float*)d_in[5];
    const float* ar    = (const float*)d_in[6];
    const float* semW  = (const float*)d_in[7];
    const float* semb  = (const float*)d_in[8];
    const float* semq  = (const float*)d_in[9];
    const float* foW   = (const float*)d_in[10];
    const float* fob   = (const float*)d_in[11];
    const int* type_idx = (const int*)d_in[12];
    const int* node_idx = (const int*)d_in[13];
    const int* edge_src = (const int*)d_in[14];
    const int* edge_dst = (const int*)d_in[15];
    const int* tgt_idx  = (const int*)d_in[16];
    float* out = (float*)d_out;

    char* ws = (char*)d_ws;
    size_t off = 0;
    auto alloc = [&](size_t bytes) -> void* {
        void* p = ws + off;
        off = (off + bytes + 255) & ~(size_t)255;
        return p;
    };
    float* transformed = (float*)alloc((size_t)NT * 64 * 4);
    float* z           = (float*)alloc((size_t)NPG * 256 * 4);
    float* el          = (float*)alloc((size_t)NPG * 4 * 4);
    float* er          = (float*)alloc((size_t)NPG * 4 * 4);
    float* metas       = (float*)alloc((size_t)2 * TT * 256 * 4);
    float* wsum        = (float*)alloc(64);
    int*   deg         = (int*)alloc((size_t)NPG * 4);
    int*   offsets     = (int*)alloc((size_t)(NPG + 1) * 4);
    int*   cursor      = (int*)alloc((size_t)NPG * 4);
    int*   perm        = (int*)alloc((size_t)EG * 4);

    fc_kernel<<<dim3(782, 2), 256, 0, stream>>>(f0, f1, fcW, fcb, type_idx,
                                                transformed);
    const int eblocks = (EG + 255) / 256;
    for (int b = 0; b < 2; ++b) {
        for (int m = 0; m < 2; ++m) {
            int g = b * 2 + m;
            hipMemsetAsync(deg, 0, (size_t)NPG * 4, stream);
            count_kernel<<<eblocks, 256, 0, stream>>>(edge_dst + (size_t)g * EG, deg);
            scan_kernel<<<1, 1024, 0, stream>>>(deg, offsets, cursor);
            scatter_kernel<<<eblocks, 256, 0, stream>>>(
                edge_dst + (size_t)g * EG, edge_src + (size_t)g * EG, cursor, perm);
            z_kernel<<<782, 256, 0, stream>>>(
                transformed, node_idx + (size_t)g * NPG, gatW + (size_t)g * 64 * 256, z);
            elr_kernel<<<12500, 256, 0, stream>>>(
                z, al + (size_t)g * 256, ar + (size_t)g * 256, el, er);
            agg_kernel<<<TT, 256, 0, stream>>>(
                tgt_idx + (size_t)g * TT, offsets, perm, el, er, z,
                metas + (size_t)m * TT * 256);
        }
        hipMemsetAsync(wsum, 0, 2 * 4, stream);
        sem_kernel<<<dim3(313, 2), 256, 0, stream>>>(
            metas, semW + (size_t)b * 256 * 256, semb + (size_t)b * 256,
            semq + (size_t)b * 256, wsum);
        out_kernel<<<313, 256, 0, stream>>>(
            metas, wsum, foW + (size_t)b * 256 * 64, fob + (size_t)b * 64,
            out + (size_t)b * TT * 64);
    }
}

// Round 3
// 834.377 us; speedup vs baseline: 2.1465x; 1.5508x over previous
//
#include <hip/hip_runtime.h>
#include <math.h>

#define NT     100000   // total nodes
#define NPT    50000    // nodes per type
#define NPG    50000    // nodes per metapath graph
#define EG     500000   // edges per graph
#define DD     256      // NH*HD
#define TT     20000    // targets per metapath
#define NPB    196      // scan partial blocks per graph (196*256 >= 50000)

typedef __attribute__((ext_vector_type(8))) short short8;   // 8 bf16 = 4 VGPRs
typedef __attribute__((ext_vector_type(4))) float f32x4;    // MFMA C/D

#define MFMA16(a, b, c) __builtin_amdgcn_mfma_f32_16x16x32_bf16((a), (b), (c), 0, 0, 0)

// RNE float->bf16, packed pair
__device__ inline unsigned pk2(float x, float y) {
    unsigned a = __float_as_uint(x); a = (a + 0x7FFFu + ((a >> 16) & 1u)) >> 16;
    unsigned b = __float_as_uint(y); b = (b + 0x7FFFu + ((b >> 16) & 1u)) >> 16;
    return (a & 0xFFFFu) | (b << 16);
}
__device__ inline int2 pk4(float4 v) {
    int2 r; r.x = (int)pk2(v.x, v.y); r.y = (int)pk2(v.z, v.w); return r;
}

// ---------------------------------------------------------------------------
// fc: transformed[type_idx[ty][r]] = features_ty @ fc_W[ty]^T + fc_b[ty]
// ---------------------------------------------------------------------------
__global__ __launch_bounds__(256) void fc_kernel(
    const float* __restrict__ f0, const float* __restrict__ f1,
    const float* __restrict__ fcW, const float* __restrict__ fcb,
    const int* __restrict__ type_idx, float* __restrict__ transformed)
{
    __shared__ short As[64 * 136];
    __shared__ short Bs[64 * 136];
    int ty = blockIdx.y;
    const float* feat = ty ? f1 : f0;
    const float* W = fcW + (size_t)ty * 64 * 256;
    int tid = threadIdx.x, wv = tid >> 6, l = tid & 63, q = l >> 4, c = l & 15;
    int rbase = blockIdx.x * 64;
    f32x4 acc[4];
#pragma unroll
    for (int i = 0; i < 4; ++i) acc[i] = (f32x4){0.f, 0.f, 0.f, 0.f};

    for (int kt = 0; kt < 2; ++kt) {
        __syncthreads();
#pragma unroll
        for (int j = 0; j < 8; ++j) {
            int e = j * 1024 + tid * 4;
            int r = e >> 7, k = e & 127;
            int2 w = make_int2(0, 0);
            if (rbase + r < NPT)
                w = pk4(*(const float4*)&feat[(size_t)(rbase + r) * 256 + kt * 128 + k]);
            *(int2*)&As[r * 136 + k] = w;
            *(int2*)&Bs[r * 136 + k] =
                pk4(*(const float4*)&W[(size_t)r * 256 + kt * 128 + k]);
        }
        __syncthreads();
        const short* Ap = &As[(wv * 16 + c) * 136 + q * 8];
        short8 af[4];
#pragma unroll
        for (int kk = 0; kk < 4; ++kk) af[kk] = *(const short8*)&Ap[kk * 32];
#pragma unroll
        for (int t4 = 0; t4 < 4; ++t4) {
            const short* Bp = &Bs[(t4 * 16 + c) * 136 + q * 8];
#pragma unroll
            for (int kk = 0; kk < 4; ++kk)
                acc[t4] = MFMA16(af[kk], *(const short8*)&Bp[kk * 32], acc[t4]);
        }
    }
    int grl = rbase + wv * 16 + q * 4;
#pragma unroll
    for (int t4 = 0; t4 < 4; ++t4) {
        int col = t4 * 16 + c;
        float bv = fcb[ty * 64 + col];
#pragma unroll
        for (int reg = 0; reg < 4; ++reg) {
            int gr = grl + reg;
            if (gr < NPT) {
                int dest = type_idx[ty * NPT + gr];
                transformed[(size_t)dest * 64 + col] = acc[t4][reg] + bv;
            }
        }
    }
}

// ---------------------------------------------------------------------------
// z = transformed[node_idx] @ gat_W : M=50000 gathered rows, K=64, N=256.
// ---------------------------------------------------------------------------
__global__ __launch_bounds__(256) void z_kernel(
    const float* __restrict__ transformed, const int* __restrict__ nidx,
    const float* __restrict__ gatW, float* __restrict__ z)
{
    __shared__ short As[64 * 72];
    __shared__ short Bs[256 * 72];
    int tid = threadIdx.x, wv = tid >> 6, l = tid & 63, q = l >> 4, c = l & 15;
    int rbase = blockIdx.x * 64;
#pragma unroll
    for (int j = 0; j < 4; ++j) {
        int e = j * 1024 + tid * 4;
        int r = e >> 6, k = e & 63;
        int2 w = make_int2(0, 0);
        if (rbase + r < NPG) {
            int n = nidx[rbase + r];
            w = pk4(*(const float4*)&transformed[(size_t)n * 64 + k]);
        }
        *(int2*)&As[r * 72 + k] = w;
    }
    {
        int n = tid;
        for (int kp = 0; kp < 32; ++kp) {
            float x = gatW[(size_t)(2 * kp) * 256 + n];
            float y = gatW[(size_t)(2 * kp + 1) * 256 + n];
            *(unsigned*)&Bs[n * 72 + 2 * kp] = pk2(x, y);
        }
    }
    __syncthreads();
    const short* Ap = &As[(wv * 16 + c) * 72 + q * 8];
    short8 a0 = *(const short8*)&Ap[0];
    short8 a1 = *(const short8*)&Ap[32];
    f32x4 acc[16];
    const f32x4 zero = (f32x4){0.f, 0.f, 0.f, 0.f};
#pragma unroll
    for (int t16 = 0; t16 < 16; ++t16) {
        const short* Bp = &Bs[(t16 * 16 + c) * 72 + q * 8];
        acc[t16] = MFMA16(a0, *(const short8*)&Bp[0], zero);
        acc[t16] = MFMA16(a1, *(const short8*)&Bp[32], acc[t16]);
    }
    int grl = rbase + wv * 16 + q * 4;
#pragma unroll
    for (int t16 = 0; t16 < 16; ++t16)
#pragma unroll
        for (int reg = 0; reg < 4; ++reg) {
            int gr = grl + reg;
            if (gr < NPG)
                z[(size_t)gr * 256 + t16 * 16 + c] = acc[t16][reg];
        }
}

// ---------------------------------------------------------------------------
// el/er per node/head
// ---------------------------------------------------------------------------
__global__ __launch_bounds__(256) void elr_kernel(
    const float* __restrict__ z, const float* __restrict__ al,
    const float* __restrict__ ar, float* __restrict__ el, float* __restrict__ er)
{
    int gid = blockIdx.x * 256 + threadIdx.x;
    int row = gid >> 6;
    int lane = threadIdx.x & 63;
    if (row >= NPG) return;
    int head = lane >> 4;
    int hd0 = (lane & 15) * 4;
    float4 zv = *(const float4*)&z[(size_t)row * 256 + lane * 4];
    float4 alv = *(const float4*)&al[head * 64 + hd0];
    float4 arv = *(const float4*)&ar[head * 64 + hd0];
    float pl = zv.x * alv.x + zv.y * alv.y + zv.z * alv.z + zv.w * alv.w;
    float pr = zv.x * arv.x + zv.y * arv.y + zv.z * arv.z + zv.w * arv.w;
    for (int o = 1; o < 16; o <<= 1) {
        pl += __shfl_xor(pl, o);
        pr += __shfl_xor(pr, o);
    }
    if ((lane & 15) == 0) {
        el[row * 4 + head] = pl;
        er[row * 4 + head] = pr;
    }
}

// ---------------------------------------------------------------------------
// CSR build, batched over all 4 graphs (blockIdx.y = graph)
// ---------------------------------------------------------------------------
__global__ __launch_bounds__(256) void count4_kernel(
    const int* __restrict__ dst, int* __restrict__ deg4)
{
    int g = blockIdx.y;
    int e = blockIdx.x * 256 + threadIdx.x;
    if (e < EG) atomicAdd(&deg4[g * NPG + dst[(size_t)g * EG + e]], 1);
}

__device__ inline int block_excl_scan(int v, int tid) {
    __shared__ int wtot[4];
    int lane = tid & 63, w = tid >> 6;
    int x = v;
#pragma unroll
    for (int o = 1; o < 64; o <<= 1) {
        int y = __shfl_up(x, o);
        if (lane >= o) x += y;
    }
    if (lane == 63) wtot[w] = x;
    __syncthreads();
    if (tid == 0) {
        int s = 0;
#pragma unroll
        for (int i = 0; i < 4; ++i) { int t = wtot[i]; wtot[i] = s; s += t; }
    }
    __syncthreads();
    return wtot[w] + x - v;
}

__global__ __launch_bounds__(256) void partial4_kernel(
    const int* __restrict__ deg4, int* __restrict__ part4)
{
    int g = blockIdx.y;
    int i = blockIdx.x * 256 + threadIdx.x;
    int v = (i < NPG) ? deg4[g * NPG + i] : 0;
#pragma unroll
    for (int o = 32; o > 0; o >>= 1) v += __shfl_xor(v, o);
    __shared__ int ws4[4];
    if ((threadIdx.x & 63) == 0) ws4[threadIdx.x >> 6] = v;
    __syncthreads();
    if (threadIdx.x == 0)
        part4[g * NPB + blockIdx.x] = ws4[0] + ws4[1] + ws4[2] + ws4[3];
}

__global__ __launch_bounds__(256) void scanp_kernel(
    const int* __restrict__ part4, int* __restrict__ pref4,
    int* __restrict__ offsets4)
{
    int g = blockIdx.y;
    int t = threadIdx.x;
    int v = (t < NPB) ? part4[g * NPB + t] : 0;
    int e = block_excl_scan(v, t);
    if (t < NPB) pref4[g * NPB + t] = e;
    if (t == 255) offsets4[(size_t)g * (NPG + 1) + NPG] = e + v;  // total
}

__global__ __launch_bounds__(256) void distribute_kernel(
    const int* __restrict__ deg4, const int* __restrict__ pref4,
    int* __restrict__ offsets4, int* __restrict__ cursor4)
{
    int g = blockIdx.y;
    int i = blockIdx.x * 256 + threadIdx.x;
    int v = (i < NPG) ? deg4[g * NPG + i] : 0;
    int e = block_excl_scan(v, threadIdx.x);
    if (i < NPG) {
        int off = pref4[g * NPB + blockIdx.x] + e;
        offsets4[(size_t)g * (NPG + 1) + i] = off;
        cursor4[g * NPG + i] = off;
    }
}

__global__ __launch_bounds__(256) void scatter4_kernel(
    const int* __restrict__ dst, const int* __restrict__ src,
    int* __restrict__ cursor4, int* __restrict__ perm4)
{
    int g = blockIdx.y;
    int e = blockIdx.x * 256 + threadIdx.x;
    if (e < EG) {
        int d = dst[(size_t)g * EG + e];
        int pos = atomicAdd(&cursor4[g * NPG + d], 1);
        perm4[(size_t)g * EG + pos] = src[(size_t)g * EG + e];
    }
}

// ---------------------------------------------------------------------------
// Aggregation: one block per target, one wave per head.
// 4 edge slots x 16 dim-lanes (float4) -> 4 edges in flight per wave.
// ---------------------------------------------------------------------------
__global__ __launch_bounds__(256) void agg_kernel(
    const int* __restrict__ tgt, const int* __restrict__ offsets,
    const int* __restrict__ perm, const float* __restrict__ el,
    const float* __restrict__ er, const float* __restrict__ z,
    float* __restrict__ meta)
{
    int t = blockIdx.x;
    int h = threadIdx.x >> 6;
    int lane = threadIdx.x & 63;
    int slot = lane >> 4, d4 = (lane & 15) * 4;
    int dstn = tgt[t];
    int start = offsets[dstn], end = offsets[dstn + 1];
    float erv = er[dstn * 4 + h];
    // pass 1: max (lane-parallel over edges)
    float mx = -INFINITY;
    for (int i = start + lane; i < end; i += 64) {
        float v = el[perm[i] * 4 + h] + erv;
        v = v > 0.f ? v : 0.2f * v;
        mx = fmaxf(mx, v);
    }
#pragma unroll
    for (int o = 32; o > 0; o >>= 1) mx = fmaxf(mx, __shfl_xor(mx, o));
    // pass 2: 4 edge slots in parallel, each lane owns 4 dims
    float4 accv = {0.f, 0.f, 0.f, 0.f};
    float denom = 0.f;
    for (int i = start + slot; i < end; i += 4) {
        int s = perm[i];
        float v = el[s * 4 + h] + erv;
        v = v > 0.f ? v : 0.2f * v;
        float ex = __expf(v - mx);
        denom += ex;
        float4 zv = *(const float4*)&z[(size_t)s * 256 + h * 64 + d4];
        accv.x += ex * zv.x; accv.y += ex * zv.y;
        accv.z += ex * zv.z; accv.w += ex * zv.w;
    }
#pragma unroll
    for (int o = 16; o < 64; o <<= 1) {
        denom += __shfl_xor(denom, o);
        accv.x += __shfl_xor(accv.x, o);
        accv.y += __shfl_xor(accv.y, o);
        accv.z += __shfl_xor(accv.z, o);
        accv.w += __shfl_xor(accv.w, o);
    }
    if (slot == 0) {
        float inv = 1.f / (denom + 1e-9f);
        float4 o4;
        o4.x = accv.x * inv; o4.y = accv.y * inv;
        o4.z = accv.z * inv; o4.w = accv.w * inv;
        o4.x = o4.x > 0.f ? o4.x : expm1f(o4.x);
        o4.y = o4.y > 0.f ? o4.y : expm1f(o4.y);
        o4.z = o4.z > 0.f ? o4.z : expm1f(o4.z);
        o4.w = o4.w > 0.f ? o4.w : expm1f(o4.w);
        *(float4*)&meta[(size_t)t * 256 + h * 64 + d4] = o4;
    }
}

// ---------------------------------------------------------------------------
// Semantic logits: wsum += sum_t tanh(meta[t]@W + b)@q
// ---------------------------------------------------------------------------
__global__ __launch_bounds__(256) void sem_kernel(
    const float* __restrict__ metas, const float* __restrict__ semW,
    const float* __restrict__ semb, const float* __restrict__ semq,
    float* __restrict__ wsum)
{
    __shared__ short As[64 * 72];
    __shared__ short Bs[256 * 72];
    __shared__ float bsum;
    int m = blockIdx.y;
    const float* A = metas + (size_t)m * TT * 256;
    int tid = threadIdx.x, wv = tid >> 6, l = tid & 63, q = l >> 4, c = l & 15;
    if (tid == 0) bsum = 0.f;
    int rbase = blockIdx.x * 64;
    f32x4 acc[16];
#pragma unroll
    for (int i = 0; i < 16; ++i) acc[i] = (f32x4){0.f, 0.f, 0.f, 0.f};

    for (int kt = 0; kt < 4; ++kt) {
        __syncthreads();
#pragma unroll
        for (int j = 0; j < 4; ++j) {
            int e = j * 1024 + tid * 4;
            int r = e >> 6, k = e & 63;
            int2 w = make_int2(0, 0);
            if (rbase + r < TT)
                w = pk4(*(const float4*)&A[(size_t)(rbase + r) * 256 + kt * 64 + k]);
            *(int2*)&As[r * 72 + k] = w;
        }
        {
            int n = tid;
            for (int kp = 0; kp < 32; ++kp) {
                float x = semW[(size_t)(kt * 64 + 2 * kp) * 256 + n];
                float y = semW[(size_t)(kt * 64 + 2 * kp + 1) * 256 + n];
                *(unsigned*)&Bs[n * 72 + 2 * kp] = pk2(x, y);
            }
        }
        __syncthreads();
        const short* Ap = &As[(wv * 16 + c) * 72 + q * 8];
        short8 a0 = *(const short8*)&Ap[0];
        short8 a1 = *(const short8*)&Ap[32];
#pragma unroll
        for (int t16 = 0; t16 < 16; ++t16) {
            const short* Bp = &Bs[(t16 * 16 + c) * 72 + q * 8];
            acc[t16] = MFMA16(a0, *(const short8*)&Bp[0], acc[t16]);
            acc[t16] = MFMA16(a1, *(const short8*)&Bp[32], acc[t16]);
        }
    }
    float part = 0.f;
    int grl = rbase + wv * 16 + q * 4;
#pragma unroll
    for (int t16 = 0; t16 < 16; ++t16) {
        int col = t16 * 16 + c;
        float bb = semb[col], qq = semq[col];
#pragma unroll
        for (int reg = 0; reg < 4; ++reg)
            if (grl + reg < TT) part += tanhf(acc[t16][reg] + bb) * qq;
    }
    for (int o = 32; o > 0; o >>= 1) part += __shfl_xor(part, o);
    if (l == 0) atomicAdd(&bsum, part);
    __syncthreads();
    if (tid == 0) atomicAdd(&wsum[m], bsum);
}

// ---------------------------------------------------------------------------
// Output: beta = softmax(wsum/T); s = b0*meta0+b1*meta1; out = s@foW + fob
// ---------------------------------------------------------------------------
__global__ __launch_bounds__(256) void out_kernel(
    const float* __restrict__ metas, const float* __restrict__ wsum,
    const float* __restrict__ foW, const float* __restrict__ fob,
    float* __restrict__ out)
{
    __shared__ short As[64 * 136];
    __shared__ short Bs[64 * 136];
    int tid = threadIdx.x, wv = tid >> 6, l = tid & 63, q = l >> 4, c = l & 15;
    float w0 = wsum[0] * (1.f / TT), w1 = wsum[1] * (1.f / TT);
    float mxv = fmaxf(w0, w1);
    float e0 = __expf(w0 - mxv), e1 = __expf(w1 - mxv);
    float inv = 1.f / (e0 + e1);
    float b0 = e0 * inv, b1 = e1 * inv;
    int rbase = blockIdx.x * 64;
    f32x4 acc[4];
#pragma unroll
    for (int i = 0; i < 4; ++i) acc[i] = (f32x4){0.f, 0.f, 0.f, 0.f};

    for (int kt = 0; kt < 2; ++kt) {
        __syncthreads();
#pragma unroll
        for (int j = 0; j < 8; ++j) {
            int e = j * 1024 + tid * 4;
            int r = e >> 7, k = e & 127;
            int2 w = make_int2(0, 0);
            if (rbase + r < TT) {
                const float* p0 = &metas[(size_t)(rbase + r) * 256 + kt * 128 + k];
                float4 va = *(const float4*)p0;
                float4 vb = *(const float4*)(p0 + (size_t)TT * 256);
                float4 s;
                s.x = b0 * va.x + b1 * vb.x;
                s.y = b0 * va.y + b1 * vb.y;
                s.z = b0 * va.z + b1 * vb.z;
                s.w = b0 * va.w + b1 * vb.w;
                w = pk4(s);
            }
            *(int2*)&As[r * 136 + k] = w;
        }
        {
            int n = tid & 63, kh = tid >> 6;
            for (int kp = 0; kp < 16; ++kp) {
                int k = kh * 32 + 2 * kp;
                float x = foW[(size_t)(kt * 128 + k) * 64 + n];
                float y = foW[(size_t)(kt * 128 + k + 1) * 64 + n];
                *(unsigned*)&Bs[n * 136 + k] = pk2(x, y);
            }
        }
        __syncthreads();
        const short* Ap = &As[(wv * 16 + c) * 136 + q * 8];
        short8 af[4];
#pragma unroll
        for (int kk = 0; kk < 4; ++kk) af[kk] = *(const short8*)&Ap[kk * 32];
#pragma unroll
        for (int t4 = 0; t4 < 4; ++t4) {
            const short* Bp = &Bs[(t4 * 16 + c) * 136 + q * 8];
#pragma unroll
            for (int kk = 0; kk < 4; ++kk)
                acc[t4] = MFMA16(af[kk], *(const short8*)&Bp[kk * 32], acc[t4]);
        }
    }
    int grl = rbase + wv * 16 + q * 4;
#pragma unroll
    for (int t4 = 0; t4 < 4; ++t4) {
        int col = t4 * 16 + c;
        float bv = fob[col];
#pragma unroll
        for (int reg = 0; reg < 4; ++reg) {
            int gr = grl + reg;
            if (gr < TT)
                out[(size_t)gr * 64 + col] = acc[t4][reg] + bv;
        }
    }
}

// ---------------------------------------------------------------------------
extern "C" void kernel_launch(void* const* d_in, const int* in_sizes, int n_in,
                              void* d_out, int out_size, void* d_ws, size_t ws_size,
                              hipStream_t stream)
{
    const float* f0    = (const float*)d_in[0];
    const float* f1    = (const float*)d_in[1];
    const float* fcW   = (const float*)d_in[2];
    const float* fcb   = (const float*)d_in[3];
    const float* gatW  = (const float*)d_in[4];
    const float* al    = (const float*)d_in[5];
    const float* ar    = (const float*)d_in[6];
    const float* semW  = (const float*)d_in[7];
    const float* semb  = (const float*)d_in[8];
    const float* semq  = (const float*)d_in[9];
    const float* foW   = (const float*)d_in[10];
    const float* fob   = (const float*)d_in[11];
    const int* type_idx = (const int*)d_in[12];
    const int* node_idx = (const int*)d_in[13];
    const int* edge_src = (const int*)d_in[14];
    const int* edge_dst = (const int*)d_in[15];
    const int* tgt_idx  = (const int*)d_in[16];
    float* out = (float*)d_out;

    char* ws = (char*)d_ws;
    size_t off = 0;
    auto alloc = [&](size_t bytes) -> void* {
        void* p = ws + off;
        off = (off + bytes + 255) & ~(size_t)255;
        return p;
    };
    float* transformed = (float*)alloc((size_t)NT * 64 * 4);
    float* z           = (float*)alloc((size_t)NPG * 256 * 4);
    float* el          = (float*)alloc((size_t)NPG * 4 * 4);
    float* er          = (float*)alloc((size_t)NPG * 4 * 4);
    float* metas       = (float*)alloc((size_t)2 * TT * 256 * 4);
    float* wsum4       = (float*)alloc(64);
    int*   deg4        = (int*)alloc((size_t)4 * NPG * 4);
    int*   offsets4    = (int*)alloc((size_t)4 * (NPG + 1) * 4);
    int*   cursor4     = (int*)alloc((size_t)4 * NPG * 4);
    int*   perm4       = (int*)alloc((size_t)4 * EG * 4);
    int*   part4       = (int*)alloc((size_t)4 * NPB * 4);
    int*   pref4       = (int*)alloc((size_t)4 * NPB * 4);

    const int eblocks = (EG + 255) / 256;

    // --- batched CSR build for all 4 graphs ---
    hipMemsetAsync(deg4, 0, (size_t)4 * NPG * 4, stream);
    hipMemsetAsync(wsum4, 0, 16, stream);
    count4_kernel<<<dim3(eblocks, 4), 256, 0, stream>>>(edge_dst, deg4);
    partial4_kernel<<<dim3(NPB, 4), 256, 0, stream>>>(deg4, part4);
    scanp_kernel<<<dim3(1, 4), 256, 0, stream>>>(part4, pref4, offsets4);
    distribute_kernel<<<dim3(NPB, 4), 256, 0, stream>>>(deg4, pref4, offsets4,
                                                        cursor4);
    scatter4_kernel<<<dim3(eblocks, 4), 256, 0, stream>>>(edge_dst, edge_src,
                                                          cursor4, perm4);

    fc_kernel<<<dim3(782, 2), 256, 0, stream>>>(f0, f1, fcW, fcb, type_idx,
                                                transformed);
    for (int b = 0; b < 2; ++b) {
        for (int m = 0; m < 2; ++m) {
            int g = b * 2 + m;
            z_kernel<<<782, 256, 0, stream>>>(
                transformed, node_idx + (size_t)g * NPG, gatW + (size_t)g * 64 * 256, z);
            elr_kernel<<<12500, 256, 0, stream>>>(
                z, al + (size_t)g * 256, ar + (size_t)g * 256, el, er);
            agg_kernel<<<TT, 256, 0, stream>>>(
                tgt_idx + (size_t)g * TT, offsets4 + (size_t)g * (NPG + 1),
                perm4 + (size_t)g * EG, el, er, z, metas + (size_t)m * TT * 256);
        }
        sem_kernel<<<dim3(313, 2), 256, 0, stream>>>(
            metas, semW + (size_t)b * 256 * 256, semb + (size_t)b * 256,
            semq + (size_t)b * 256, wsum4 + b * 2);
        out_kernel<<<313, 256, 0, stream>>>(
            metas, wsum4 + b * 2, foW + (size_t)b * 256 * 64, fob + (size_t)b * 64,
            out + (size_t)b * TT * 64);
    }
}

// Round 4
// 658.180 us; speedup vs baseline: 2.7211x; 1.2677x over previous
//
#include <hip/hip_runtime.h>
#include <math.h>

#define NT     100000   // total nodes
#define NPT    50000    // nodes per type
#define NPG    50000    // nodes per metapath graph
#define EG     500000   // edges per graph
#define DD     256      // NH*HD
#define TT     20000    // targets per metapath
#define NPB    196      // scan partial blocks per graph (196*256 >= 50000)

typedef __attribute__((ext_vector_type(8))) short short8;   // 8 bf16 = 4 VGPRs
typedef __attribute__((ext_vector_type(4))) float f32x4;    // MFMA C/D

#define MFMA16(a, b, c) __builtin_amdgcn_mfma_f32_16x16x32_bf16((a), (b), (c), 0, 0, 0)

// RNE float->bf16, packed pair
__device__ inline unsigned pk2(float x, float y) {
    unsigned a = __float_as_uint(x); a = (a + 0x7FFFu + ((a >> 16) & 1u)) >> 16;
    unsigned b = __float_as_uint(y); b = (b + 0x7FFFu + ((b >> 16) & 1u)) >> 16;
    return (a & 0xFFFFu) | (b << 16);
}
__device__ inline int2 pk4(float4 v) {
    int2 r; r.x = (int)pk2(v.x, v.y); r.y = (int)pk2(v.z, v.w); return r;
}

// ---------------------------------------------------------------------------
// fc: transformed[type_idx[ty][r]] = features_ty @ fc_W[ty]^T + fc_b[ty]
// ---------------------------------------------------------------------------
__global__ __launch_bounds__(256) void fc_kernel(
    const float* __restrict__ f0, const float* __restrict__ f1,
    const float* __restrict__ fcW, const float* __restrict__ fcb,
    const int* __restrict__ type_idx, float* __restrict__ transformed)
{
    __shared__ short As[64 * 136];
    __shared__ short Bs[64 * 136];
    int ty = blockIdx.y;
    const float* feat = ty ? f1 : f0;
    const float* W = fcW + (size_t)ty * 64 * 256;
    int tid = threadIdx.x, wv = tid >> 6, l = tid & 63, q = l >> 4, c = l & 15;
    int rbase = blockIdx.x * 64;
    f32x4 acc[4];
#pragma unroll
    for (int i = 0; i < 4; ++i) acc[i] = (f32x4){0.f, 0.f, 0.f, 0.f};

    for (int kt = 0; kt < 2; ++kt) {
        __syncthreads();
#pragma unroll
        for (int j = 0; j < 8; ++j) {
            int e = j * 1024 + tid * 4;
            int r = e >> 7, k = e & 127;
            int2 w = make_int2(0, 0);
            if (rbase + r < NPT)
                w = pk4(*(const float4*)&feat[(size_t)(rbase + r) * 256 + kt * 128 + k]);
            *(int2*)&As[r * 136 + k] = w;
            *(int2*)&Bs[r * 136 + k] =
                pk4(*(const float4*)&W[(size_t)r * 256 + kt * 128 + k]);
        }
        __syncthreads();
        const short* Ap = &As[(wv * 16 + c) * 136 + q * 8];
        short8 af[4];
#pragma unroll
        for (int kk = 0; kk < 4; ++kk) af[kk] = *(const short8*)&Ap[kk * 32];
#pragma unroll
        for (int t4 = 0; t4 < 4; ++t4) {
            const short* Bp = &Bs[(t4 * 16 + c) * 136 + q * 8];
#pragma unroll
            for (int kk = 0; kk < 4; ++kk)
                acc[t4] = MFMA16(af[kk], *(const short8*)&Bp[kk * 32], acc[t4]);
        }
    }
    int grl = rbase + wv * 16 + q * 4;
#pragma unroll
    for (int t4 = 0; t4 < 4; ++t4) {
        int col = t4 * 16 + c;
        float bv = fcb[ty * 64 + col];
#pragma unroll
        for (int reg = 0; reg < 4; ++reg) {
            int gr = grl + reg;
            if (gr < NPT) {
                int dest = type_idx[ty * NPT + gr];
                transformed[(size_t)dest * 64 + col] = acc[t4][reg] + bv;
            }
        }
    }
}

// ---------------------------------------------------------------------------
// z = transformed[node_idx] @ gat_W, with fused el/er epilogue.
// M=50000 gathered rows, K=64, N=256.
// ---------------------------------------------------------------------------
__global__ __launch_bounds__(256) void z_kernel(
    const float* __restrict__ transformed, const int* __restrict__ nidx,
    const float* __restrict__ gatW, const float* __restrict__ al,
    const float* __restrict__ ar, float* __restrict__ z,
    float* __restrict__ el, float* __restrict__ er)
{
    __shared__ short As[64 * 72];
    __shared__ short Bs[256 * 72];
    int tid = threadIdx.x, wv = tid >> 6, l = tid & 63, q = l >> 4, c = l & 15;
    int rbase = blockIdx.x * 64;
#pragma unroll
    for (int j = 0; j < 4; ++j) {
        int e = j * 1024 + tid * 4;
        int r = e >> 6, k = e & 63;
        int2 w = make_int2(0, 0);
        if (rbase + r < NPG) {
            int n = nidx[rbase + r];
            w = pk4(*(const float4*)&transformed[(size_t)n * 64 + k]);
        }
        *(int2*)&As[r * 72 + k] = w;
    }
    {
        int n = tid;
        for (int kp = 0; kp < 32; ++kp) {
            float x = gatW[(size_t)(2 * kp) * 256 + n];
            float y = gatW[(size_t)(2 * kp + 1) * 256 + n];
            *(unsigned*)&Bs[n * 72 + 2 * kp] = pk2(x, y);
        }
    }
    __syncthreads();
    const short* Ap = &As[(wv * 16 + c) * 72 + q * 8];
    short8 a0 = *(const short8*)&Ap[0];
    short8 a1 = *(const short8*)&Ap[32];
    f32x4 acc[16];
    const f32x4 zero = (f32x4){0.f, 0.f, 0.f, 0.f};
#pragma unroll
    for (int t16 = 0; t16 < 16; ++t16) {
        const short* Bp = &Bs[(t16 * 16 + c) * 72 + q * 8];
        acc[t16] = MFMA16(a0, *(const short8*)&Bp[0], zero);
        acc[t16] = MFMA16(a1, *(const short8*)&Bp[32], acc[t16]);
    }
    int grl = rbase + wv * 16 + q * 4;
#pragma unroll
    for (int t16 = 0; t16 < 16; ++t16)
#pragma unroll
        for (int reg = 0; reg < 4; ++reg) {
            int gr = grl + reg;
            if (gr < NPG)
                z[(size_t)gr * 256 + t16 * 16 + c] = acc[t16][reg];
        }
    // fused el/er: head h = t16>>2 (cols t16*16+c); butterfly over c lanes
    float pl[4][4], pr[4][4];   // [reg][h]
#pragma unroll
    for (int reg = 0; reg < 4; ++reg)
#pragma unroll
        for (int h = 0; h < 4; ++h) { pl[reg][h] = 0.f; pr[reg][h] = 0.f; }
#pragma unroll
    for (int t16 = 0; t16 < 16; ++t16) {
        int col = t16 * 16 + c, h = t16 >> 2;
        float alv = al[col], arv = ar[col];
#pragma unroll
        for (int reg = 0; reg < 4; ++reg) {
            pl[reg][h] += acc[t16][reg] * alv;
            pr[reg][h] += acc[t16][reg] * arv;
        }
    }
#pragma unroll
    for (int o = 1; o < 16; o <<= 1)
#pragma unroll
        for (int reg = 0; reg < 4; ++reg)
#pragma unroll
            for (int h = 0; h < 4; ++h) {
                pl[reg][h] += __shfl_xor(pl[reg][h], o);
                pr[reg][h] += __shfl_xor(pr[reg][h], o);
            }
    if (c == 0) {
#pragma unroll
        for (int reg = 0; reg < 4; ++reg) {
            int gr = grl + reg;
            if (gr < NPG) {
                float4 vl = {pl[reg][0], pl[reg][1], pl[reg][2], pl[reg][3]};
                float4 vr = {pr[reg][0], pr[reg][1], pr[reg][2], pr[reg][3]};
                *(float4*)&el[gr * 4] = vl;
                *(float4*)&er[gr * 4] = vr;
            }
        }
    }
}

// ---------------------------------------------------------------------------
// CSR build over TARGET nodes only, batched over all 4 graphs.
// ---------------------------------------------------------------------------
__global__ __launch_bounds__(256) void mark_kernel(
    const int* __restrict__ tgt, int* __restrict__ tflag4)
{
    int g = blockIdx.y;
    int i = blockIdx.x * 256 + threadIdx.x;
    if (i < TT) tflag4[g * NPG + tgt[(size_t)g * TT + i]] = 1;
}

__global__ __launch_bounds__(256) void count4_kernel(
    const int* __restrict__ dst, const int* __restrict__ tflag4,
    int* __restrict__ deg4)
{
    int g = blockIdx.y;
    int e = blockIdx.x * 256 + threadIdx.x;
    if (e < EG) {
        int d = dst[(size_t)g * EG + e];
        if (tflag4[g * NPG + d]) atomicAdd(&deg4[g * NPG + d], 1);
    }
}

__device__ inline int block_excl_scan(int v, int tid) {
    __shared__ int wtot[4];
    int lane = tid & 63, w = tid >> 6;
    int x = v;
#pragma unroll
    for (int o = 1; o < 64; o <<= 1) {
        int y = __shfl_up(x, o);
        if (lane >= o) x += y;
    }
    if (lane == 63) wtot[w] = x;
    __syncthreads();
    if (tid == 0) {
        int s = 0;
#pragma unroll
        for (int i = 0; i < 4; ++i) { int t = wtot[i]; wtot[i] = s; s += t; }
    }
    __syncthreads();
    return wtot[w] + x - v;
}

__global__ __launch_bounds__(256) void partial4_kernel(
    const int* __restrict__ deg4, int* __restrict__ part4)
{
    int g = blockIdx.y;
    int i = blockIdx.x * 256 + threadIdx.x;
    int v = (i < NPG) ? deg4[g * NPG + i] : 0;
#pragma unroll
    for (int o = 32; o > 0; o >>= 1) v += __shfl_xor(v, o);
    __shared__ int ws4[4];
    if ((threadIdx.x & 63) == 0) ws4[threadIdx.x >> 6] = v;
    __syncthreads();
    if (threadIdx.x == 0)
        part4[g * NPB + blockIdx.x] = ws4[0] + ws4[1] + ws4[2] + ws4[3];
}

__global__ __launch_bounds__(256) void scanp_kernel(
    const int* __restrict__ part4, int* __restrict__ pref4,
    int* __restrict__ offsets4)
{
    int g = blockIdx.y;
    int t = threadIdx.x;
    int v = (t < NPB) ? part4[g * NPB + t] : 0;
    int e = block_excl_scan(v, t);
    if (t < NPB) pref4[g * NPB + t] = e;
    if (t == 255) offsets4[(size_t)g * (NPG + 1) + NPG] = e + v;  // total
}

__global__ __launch_bounds__(256) void distribute_kernel(
    const int* __restrict__ deg4, const int* __restrict__ pref4,
    int* __restrict__ offsets4, int* __restrict__ cursor4)
{
    int g = blockIdx.y;
    int i = blockIdx.x * 256 + threadIdx.x;
    int v = (i < NPG) ? deg4[g * NPG + i] : 0;
    int e = block_excl_scan(v, threadIdx.x);
    if (i < NPG) {
        int off = pref4[g * NPB + blockIdx.x] + e;
        offsets4[(size_t)g * (NPG + 1) + i] = off;
        cursor4[g * NPG + i] = off;
    }
}

__global__ __launch_bounds__(256) void scatter4_kernel(
    const int* __restrict__ dst, const int* __restrict__ src,
    const int* __restrict__ tflag4, int* __restrict__ cursor4,
    int* __restrict__ perm4)
{
    int g = blockIdx.y;
    int e = blockIdx.x * 256 + threadIdx.x;
    if (e < EG) {
        int d = dst[(size_t)g * EG + e];
        if (tflag4[g * NPG + d]) {
            int pos = atomicAdd(&cursor4[g * NPG + d], 1);
            perm4[(size_t)g * EG + pos] = src[(size_t)g * EG + e];
        }
    }
}

// ---------------------------------------------------------------------------
// Aggregation: one block per target, one wave per head.
// 4 edge slots x 16 dim-lanes (float4) -> 4 edges in flight per wave.
// ---------------------------------------------------------------------------
__global__ __launch_bounds__(256) void agg_kernel(
    const int* __restrict__ tgt, const int* __restrict__ offsets,
    const int* __restrict__ perm, const float* __restrict__ el,
    const float* __restrict__ er, const float* __restrict__ z,
    float* __restrict__ meta)
{
    int t = blockIdx.x;
    int h = threadIdx.x >> 6;
    int lane = threadIdx.x & 63;
    int slot = lane >> 4, d4 = (lane & 15) * 4;
    int dstn = tgt[t];
    int start = offsets[dstn], end = offsets[dstn + 1];
    float erv = er[dstn * 4 + h];
    float mx = -INFINITY;
    for (int i = start + lane; i < end; i += 64) {
        float v = el[perm[i] * 4 + h] + erv;
        v = v > 0.f ? v : 0.2f * v;
        mx = fmaxf(mx, v);
    }
#pragma unroll
    for (int o = 32; o > 0; o >>= 1) mx = fmaxf(mx, __shfl_xor(mx, o));
    float4 accv = {0.f, 0.f, 0.f, 0.f};
    float denom = 0.f;
    for (int i = start + slot; i < end; i += 4) {
        int s = perm[i];
        float v = el[s * 4 + h] + erv;
        v = v > 0.f ? v : 0.2f * v;
        float ex = __expf(v - mx);
        denom += ex;
        float4 zv = *(const float4*)&z[(size_t)s * 256 + h * 64 + d4];
        accv.x += ex * zv.x; accv.y += ex * zv.y;
        accv.z += ex * zv.z; accv.w += ex * zv.w;
    }
#pragma unroll
    for (int o = 16; o < 64; o <<= 1) {
        denom += __shfl_xor(denom, o);
        accv.x += __shfl_xor(accv.x, o);
        accv.y += __shfl_xor(accv.y, o);
        accv.z += __shfl_xor(accv.z, o);
        accv.w += __shfl_xor(accv.w, o);
    }
    if (slot == 0) {
        float inv = 1.f / (denom + 1e-9f);
        float4 o4;
        o4.x = accv.x * inv; o4.y = accv.y * inv;
        o4.z = accv.z * inv; o4.w = accv.w * inv;
        o4.x = o4.x > 0.f ? o4.x : expm1f(o4.x);
        o4.y = o4.y > 0.f ? o4.y : expm1f(o4.y);
        o4.z = o4.z > 0.f ? o4.z : expm1f(o4.z);
        o4.w = o4.w > 0.f ? o4.w : expm1f(o4.w);
        *(float4*)&meta[(size_t)t * 256 + h * 64 + d4] = o4;
    }
}

// ---------------------------------------------------------------------------
// Semantic logits: wsum += sum_t tanh(meta[t]@W + b)@q
// ---------------------------------------------------------------------------
__global__ __launch_bounds__(256) void sem_kernel(
    const float* __restrict__ metas, const float* __restrict__ semW,
    const float* __restrict__ semb, const float* __restrict__ semq,
    float* __restrict__ wsum)
{
    __shared__ short As[64 * 72];
    __shared__ short Bs[256 * 72];
    __shared__ float bsum;
    int m = blockIdx.y;
    const float* A = metas + (size_t)m * TT * 256;
    int tid = threadIdx.x, wv = tid >> 6, l = tid & 63, q = l >> 4, c = l & 15;
    if (tid == 0) bsum = 0.f;
    int rbase = blockIdx.x * 64;
    f32x4 acc[16];
#pragma unroll
    for (int i = 0; i < 16; ++i) acc[i] = (f32x4){0.f, 0.f, 0.f, 0.f};

    for (int kt = 0; kt < 4; ++kt) {
        __syncthreads();
#pragma unroll
        for (int j = 0; j < 4; ++j) {
            int e = j * 1024 + tid * 4;
            int r = e >> 6, k = e & 63;
            int2 w = make_int2(0, 0);
            if (rbase + r < TT)
                w = pk4(*(const float4*)&A[(size_t)(rbase + r) * 256 + kt * 64 + k]);
            *(int2*)&As[r * 72 + k] = w;
        }
        {
            int n = tid;
            for (int kp = 0; kp < 32; ++kp) {
                float x = semW[(size_t)(kt * 64 + 2 * kp) * 256 + n];
                float y = semW[(size_t)(kt * 64 + 2 * kp + 1) * 256 + n];
                *(unsigned*)&Bs[n * 72 + 2 * kp] = pk2(x, y);
            }
        }
        __syncthreads();
        const short* Ap = &As[(wv * 16 + c) * 72 + q * 8];
        short8 a0 = *(const short8*)&Ap[0];
        short8 a1 = *(const short8*)&Ap[32];
#pragma unroll
        for (int t16 = 0; t16 < 16; ++t16) {
            const short* Bp = &Bs[(t16 * 16 + c) * 72 + q * 8];
            acc[t16] = MFMA16(a0, *(const short8*)&Bp[0], acc[t16]);
            acc[t16] = MFMA16(a1, *(const short8*)&Bp[32], acc[t16]);
        }
    }
    float part = 0.f;
    int grl = rbase + wv * 16 + q * 4;
#pragma unroll
    for (int t16 = 0; t16 < 16; ++t16) {
        int col = t16 * 16 + c;
        float bb = semb[col], qq = semq[col];
#pragma unroll
        for (int reg = 0; reg < 4; ++reg)
            if (grl + reg < TT) part += tanhf(acc[t16][reg] + bb) * qq;
    }
    for (int o = 32; o > 0; o >>= 1) part += __shfl_xor(part, o);
    if (l == 0) atomicAdd(&bsum, part);
    __syncthreads();
    if (tid == 0) atomicAdd(&wsum[m], bsum);
}

// ---------------------------------------------------------------------------
// Output: beta = softmax(wsum/T); s = b0*meta0+b1*meta1; out = s@foW + fob
// ---------------------------------------------------------------------------
__global__ __launch_bounds__(256) void out_kernel(
    const float* __restrict__ metas, const float* __restrict__ wsum,
    const float* __restrict__ foW, const float* __restrict__ fob,
    float* __restrict__ out)
{
    __shared__ short As[64 * 136];
    __shared__ short Bs[64 * 136];
    int tid = threadIdx.x, wv = tid >> 6, l = tid & 63, q = l >> 4, c = l & 15;
    float w0 = wsum[0] * (1.f / TT), w1 = wsum[1] * (1.f / TT);
    float mxv = fmaxf(w0, w1);
    float e0 = __expf(w0 - mxv), e1 = __expf(w1 - mxv);
    float inv = 1.f / (e0 + e1);
    float b0 = e0 * inv, b1 = e1 * inv;
    int rbase = blockIdx.x * 64;
    f32x4 acc[4];
#pragma unroll
    for (int i = 0; i < 4; ++i) acc[i] = (f32x4){0.f, 0.f, 0.f, 0.f};

    for (int kt = 0; kt < 2; ++kt) {
        __syncthreads();
#pragma unroll
        for (int j = 0; j < 8; ++j) {
            int e = j * 1024 + tid * 4;
            int r = e >> 7, k = e & 127;
            int2 w = make_int2(0, 0);
            if (rbase + r < TT) {
                const float* p0 = &metas[(size_t)(rbase + r) * 256 + kt * 128 + k];
                float4 va = *(const float4*)p0;
                float4 vb = *(const float4*)(p0 + (size_t)TT * 256);
                float4 s;
                s.x = b0 * va.x + b1 * vb.x;
                s.y = b0 * va.y + b1 * vb.y;
                s.z = b0 * va.z + b1 * vb.z;
                s.w = b0 * va.w + b1 * vb.w;
                w = pk4(s);
            }
            *(int2*)&As[r * 136 + k] = w;
        }
        {
            int n = tid & 63, kh = tid >> 6;
            for (int kp = 0; kp < 16; ++kp) {
                int k = kh * 32 + 2 * kp;
                float x = foW[(size_t)(kt * 128 + k) * 64 + n];
                float y = foW[(size_t)(kt * 128 + k + 1) * 64 + n];
                *(unsigned*)&Bs[n * 136 + k] = pk2(x, y);
            }
        }
        __syncthreads();
        const short* Ap = &As[(wv * 16 + c) * 136 + q * 8];
        short8 af[4];
#pragma unroll
        for (int kk = 0; kk < 4; ++kk) af[kk] = *(const short8*)&Ap[kk * 32];
#pragma unroll
        for (int t4 = 0; t4 < 4; ++t4) {
            const short* Bp = &Bs[(t4 * 16 + c) * 136 + q * 8];
#pragma unroll
            for (int kk = 0; kk < 4; ++kk)
                acc[t4] = MFMA16(af[kk], *(const short8*)&Bp[kk * 32], acc[t4]);
        }
    }
    int grl = rbase + wv * 16 + q * 4;
#pragma unroll
    for (int t4 = 0; t4 < 4; ++t4) {
        int col = t4 * 16 + c;
        float bv = fob[col];
#pragma unroll
        for (int reg = 0; reg < 4; ++reg) {
            int gr = grl + reg;
            if (gr < TT)
                out[(size_t)gr * 64 + col] = acc[t4][reg] + bv;
        }
    }
}

// ---------------------------------------------------------------------------
extern "C" void kernel_launch(void* const* d_in, const int* in_sizes, int n_in,
                              void* d_out, int out_size, void* d_ws, size_t ws_size,
                              hipStream_t stream)
{
    const float* f0    = (const float*)d_in[0];
    const float* f1    = (const float*)d_in[1];
    const float* fcW   = (const float*)d_in[2];
    const float* fcb   = (const float*)d_in[3];
    const float* gatW  = (const float*)d_in[4];
    const float* al    = (const float*)d_in[5];
    const float* ar    = (const float*)d_in[6];
    const float* semW  = (const float*)d_in[7];
    const float* semb  = (const float*)d_in[8];
    const float* semq  = (const float*)d_in[9];
    const float* foW   = (const float*)d_in[10];
    const float* fob   = (const float*)d_in[11];
    const int* type_idx = (const int*)d_in[12];
    const int* node_idx = (const int*)d_in[13];
    const int* edge_src = (const int*)d_in[14];
    const int* edge_dst = (const int*)d_in[15];
    const int* tgt_idx  = (const int*)d_in[16];
    float* out = (float*)d_out;

    char* ws = (char*)d_ws;
    size_t off = 0;
    auto alloc = [&](size_t bytes) -> void* {
        void* p = ws + off;
        off = (off + bytes + 255) & ~(size_t)255;
        return p;
    };
    float* transformed = (float*)alloc((size_t)NT * 64 * 4);
    float* z           = (float*)alloc((size_t)NPG * 256 * 4);
    float* el          = (float*)alloc((size_t)NPG * 4 * 4);
    float* er          = (float*)alloc((size_t)NPG * 4 * 4);
    float* metas       = (float*)alloc((size_t)2 * TT * 256 * 4);
    float* wsum4       = (float*)alloc(64);
    int*   deg4        = (int*)alloc((size_t)4 * NPG * 4);
    int*   tflag4      = (int*)alloc((size_t)4 * NPG * 4);
    int*   offsets4    = (int*)alloc((size_t)4 * (NPG + 1) * 4);
    int*   cursor4     = (int*)alloc((size_t)4 * NPG * 4);
    int*   perm4       = (int*)alloc((size_t)4 * EG * 4);
    int*   part4       = (int*)alloc((size_t)4 * NPB * 4);
    int*   pref4       = (int*)alloc((size_t)4 * NPB * 4);

    const int eblocks = (EG + 255) / 256;
    const int tblocks = (TT + 255) / 256;

    // --- batched target-only CSR build for all 4 graphs ---
    hipMemsetAsync(deg4, 0, (size_t)4 * NPG * 4, stream);
    hipMemsetAsync(tflag4, 0, (size_t)4 * NPG * 4, stream);
    hipMemsetAsync(wsum4, 0, 16, stream);
    mark_kernel<<<dim3(tblocks, 4), 256, 0, stream>>>(tgt_idx, tflag4);
    count4_kernel<<<dim3(eblocks, 4), 256, 0, stream>>>(edge_dst, tflag4, deg4);
    partial4_kernel<<<dim3(NPB, 4), 256, 0, stream>>>(deg4, part4);
    scanp_kernel<<<dim3(1, 4), 256, 0, stream>>>(part4, pref4, offsets4);
    distribute_kernel<<<dim3(NPB, 4), 256, 0, stream>>>(deg4, pref4, offsets4,
                                                        cursor4);
    scatter4_kernel<<<dim3(eblocks, 4), 256, 0, stream>>>(edge_dst, edge_src,
                                                          tflag4, cursor4, perm4);

    fc_kernel<<<dim3(782, 2), 256, 0, stream>>>(f0, f1, fcW, fcb, type_idx,
                                                transformed);
    for (int b = 0; b < 2; ++b) {
        for (int m = 0; m < 2; ++m) {
            int g = b * 2 + m;
            z_kernel<<<782, 256, 0, stream>>>(
                transformed, node_idx + (size_t)g * NPG, gatW + (size_t)g * 64 * 256,
                al + (size_t)g * 256, ar + (size_t)g * 256, z, el, er);
            agg_kernel<<<TT, 256, 0, stream>>>(
                tgt_idx + (size_t)g * TT, offsets4 + (size_t)g * (NPG + 1),
                perm4 + (size_t)g * EG, el, er, z, metas + (size_t)m * TT * 256);
        }
        sem_kernel<<<dim3(313, 2), 256, 0, stream>>>(
            metas, semW + (size_t)b * 256 * 256, semb + (size_t)b * 256,
            semq + (size_t)b * 256, wsum4 + b * 2);
        out_kernel<<<313, 256, 0, stream>>>(
            metas, wsum4 + b * 2, foW + (size_t)b * 256 * 64, fob + (size_t)b * 64,
            out + (size_t)b * TT * 64);
    }
}

// Round 5
// 645.506 us; speedup vs baseline: 2.7746x; 1.0196x over previous
//
#include <hip/hip_runtime.h>
#include <math.h>

#define NT     100000   // total nodes
#define NPT    50000    // nodes per type
#define NPG    50000    // nodes per metapath graph
#define EG     500000   // edges per graph
#define DD     256      // NH*HD
#define TT     20000    // targets per metapath
#define NPB    196      // scan partial blocks per graph (196*256 >= 50000)

typedef __attribute__((ext_vector_type(8))) short short8;   // 8 bf16 = 4 VGPRs
typedef __attribute__((ext_vector_type(4))) float f32x4;    // MFMA C/D
typedef unsigned short u16;

#define MFMA16(a, b, c) __builtin_amdgcn_mfma_f32_16x16x32_bf16((a), (b), (c), 0, 0, 0)

// RNE float->bf16 helpers
__device__ inline unsigned pk2(float x, float y) {
    unsigned a = __float_as_uint(x); a = (a + 0x7FFFu + ((a >> 16) & 1u)) >> 16;
    unsigned b = __float_as_uint(y); b = (b + 0x7FFFu + ((b >> 16) & 1u)) >> 16;
    return (a & 0xFFFFu) | (b << 16);
}
__device__ inline int2 pk4(float4 v) {
    int2 r; r.x = (int)pk2(v.x, v.y); r.y = (int)pk2(v.z, v.w); return r;
}
__device__ inline u16 pkb(float x) {
    unsigned a = __float_as_uint(x);
    return (u16)((a + 0x7FFFu + ((a >> 16) & 1u)) >> 16);
}
__device__ inline short8 cvt8(float4 a, float4 b) {
    union { int4 i; short8 s; } u;
    u.i = make_int4((int)pk2(a.x, a.y), (int)pk2(a.z, a.w),
                    (int)pk2(b.x, b.y), (int)pk2(b.z, b.w));
    return u.s;
}
__device__ inline float4 up4(unsigned lo, unsigned hi) {
    float4 r;
    r.x = __uint_as_float(lo << 16);
    r.y = __uint_as_float(lo & 0xFFFF0000u);
    r.z = __uint_as_float(hi << 16);
    r.w = __uint_as_float(hi & 0xFFFF0000u);
    return r;
}

// ---------------------------------------------------------------------------
// fc: tbf[type_idx[ty][r]] = bf16(features_ty @ fc_W[ty]^T + fc_b[ty])
// B staged once in LDS; A direct global->reg; one barrier.
// ---------------------------------------------------------------------------
__global__ __launch_bounds__(256) void fc_kernel(
    const float* __restrict__ f0, const float* __restrict__ f1,
    const float* __restrict__ fcW, const float* __restrict__ fcb,
    const int* __restrict__ type_idx, u16* __restrict__ tbf)
{
    __shared__ short Bs[64 * 264];
    int ty = blockIdx.y;
    const float* feat = ty ? f1 : f0;
    const float* W = fcW + (size_t)ty * 64 * 256;
    int tid = threadIdx.x, wv = tid >> 6, l = tid & 63, q = l >> 4, c = l & 15;
#pragma unroll
    for (int j = 0; j < 16; ++j) {
        int e = j * 1024 + tid * 4;
        int r = e >> 8, k = e & 255;
        *(int2*)&Bs[r * 264 + k] = pk4(*(const float4*)&W[(size_t)r * 256 + k]);
    }
    int rbase = blockIdx.x * 64;
    int row = rbase + wv * 16 + c;
    bool ok = row < NPT;
    const float* Ap = feat + (size_t)row * 256 + q * 8;
    short8 af[8];
#pragma unroll
    for (int s = 0; s < 8; ++s) {
        float4 v0 = {0.f, 0.f, 0.f, 0.f}, v1 = {0.f, 0.f, 0.f, 0.f};
        if (ok) { v0 = *(const float4*)(Ap + 32 * s); v1 = *(const float4*)(Ap + 32 * s + 4); }
        af[s] = cvt8(v0, v1);
    }
    __syncthreads();
    f32x4 acc[4];
#pragma unroll
    for (int i = 0; i < 4; ++i) acc[i] = (f32x4){0.f, 0.f, 0.f, 0.f};
#pragma unroll
    for (int s = 0; s < 8; ++s)
#pragma unroll
        for (int t4 = 0; t4 < 4; ++t4)
            acc[t4] = MFMA16(af[s],
                *(const short8*)&Bs[(t4 * 16 + c) * 264 + q * 8 + 32 * s], acc[t4]);
    int grl = rbase + wv * 16 + q * 4;
#pragma unroll
    for (int t4 = 0; t4 < 4; ++t4) {
        int col = t4 * 16 + c;
        float bv = fcb[ty * 64 + col];
#pragma unroll
        for (int reg = 0; reg < 4; ++reg) {
            int gr = grl + reg;
            if (gr < NPT) {
                int dest = type_idx[ty * NPT + gr];
                tbf[(size_t)dest * 64 + col] = pkb(acc[t4][reg] + bv);
            }
        }
    }
}

// ---------------------------------------------------------------------------
// z = tbf[node_idx] @ gat_W (bf16 out), fused el/er epilogue (fp32).
// Bt staged once (transpose); A gathered direct as bf16 short8.
// ---------------------------------------------------------------------------
__global__ __launch_bounds__(256) void z_kernel(
    const u16* __restrict__ tbf, const int* __restrict__ nidx,
    const float* __restrict__ gatW, const float* __restrict__ al,
    const float* __restrict__ ar, u16* __restrict__ zb,
    float* __restrict__ el, float* __restrict__ er)
{
    __shared__ short Bs[256 * 72];
    int tid = threadIdx.x, wv = tid >> 6, l = tid & 63, q = l >> 4, c = l & 15;
    {
        int n = tid;
        for (int kp = 0; kp < 32; ++kp) {
            float x = gatW[(size_t)(2 * kp) * 256 + n];
            float y = gatW[(size_t)(2 * kp + 1) * 256 + n];
            *(unsigned*)&Bs[n * 72 + 2 * kp] = pk2(x, y);
        }
    }
    int rbase = blockIdx.x * 64;
    int row = rbase + wv * 16 + c;
    bool ok = row < NPG;
    short8 af0 = (short8)(short)0, af1 = (short8)(short)0;
    if (ok) {
        int n = nidx[row];
        const u16* Ap = tbf + (size_t)n * 64 + q * 8;
        af0 = *(const short8*)(Ap);
        af1 = *(const short8*)(Ap + 32);
    }
    __syncthreads();
    f32x4 acc[16];
    const f32x4 zero = (f32x4){0.f, 0.f, 0.f, 0.f};
#pragma unroll
    for (int t16 = 0; t16 < 16; ++t16) {
        const short* Bp = &Bs[(t16 * 16 + c) * 72 + q * 8];
        acc[t16] = MFMA16(af0, *(const short8*)&Bp[0], zero);
        acc[t16] = MFMA16(af1, *(const short8*)&Bp[32], acc[t16]);
    }
    int grl = rbase + wv * 16 + q * 4;
#pragma unroll
    for (int t16 = 0; t16 < 16; ++t16)
#pragma unroll
        for (int reg = 0; reg < 4; ++reg) {
            int gr = grl + reg;
            if (gr < NPG)
                zb[(size_t)gr * 256 + t16 * 16 + c] = pkb(acc[t16][reg]);
        }
    // fused el/er from fp32 acc
    float pl[4][4], pr[4][4];
#pragma unroll
    for (int reg = 0; reg < 4; ++reg)
#pragma unroll
        for (int h = 0; h < 4; ++h) { pl[reg][h] = 0.f; pr[reg][h] = 0.f; }
#pragma unroll
    for (int t16 = 0; t16 < 16; ++t16) {
        int col = t16 * 16 + c, h = t16 >> 2;
        float alv = al[col], arv = ar[col];
#pragma unroll
        for (int reg = 0; reg < 4; ++reg) {
            pl[reg][h] += acc[t16][reg] * alv;
            pr[reg][h] += acc[t16][reg] * arv;
        }
    }
#pragma unroll
    for (int o = 1; o < 16; o <<= 1)
#pragma unroll
        for (int reg = 0; reg < 4; ++reg)
#pragma unroll
            for (int h = 0; h < 4; ++h) {
                pl[reg][h] += __shfl_xor(pl[reg][h], o);
                pr[reg][h] += __shfl_xor(pr[reg][h], o);
            }
    if (c == 0) {
#pragma unroll
        for (int reg = 0; reg < 4; ++reg) {
            int gr = grl + reg;
            if (gr < NPG) {
                float4 vl = {pl[reg][0], pl[reg][1], pl[reg][2], pl[reg][3]};
                float4 vr = {pr[reg][0], pr[reg][1], pr[reg][2], pr[reg][3]};
                *(float4*)&el[gr * 4] = vl;
                *(float4*)&er[gr * 4] = vr;
            }
        }
    }
}

// ---------------------------------------------------------------------------
// CSR build over TARGET nodes only, batched over all 4 graphs.
// ---------------------------------------------------------------------------
__global__ __launch_bounds__(256) void mark_kernel(
    const int* __restrict__ tgt, int* __restrict__ tflag4)
{
    int g = blockIdx.y;
    int i = blockIdx.x * 256 + threadIdx.x;
    if (i < TT) tflag4[g * NPG + tgt[(size_t)g * TT + i]] = 1;
}

__global__ __launch_bounds__(256) void count4_kernel(
    const int* __restrict__ dst, const int* __restrict__ tflag4,
    int* __restrict__ deg4)
{
    int g = blockIdx.y;
    int e = blockIdx.x * 256 + threadIdx.x;
    if (e < EG) {
        int d = dst[(size_t)g * EG + e];
        if (tflag4[g * NPG + d]) atomicAdd(&deg4[g * NPG + d], 1);
    }
}

__device__ inline int block_excl_scan(int v, int tid) {
    __shared__ int wtot[4];
    int lane = tid & 63, w = tid >> 6;
    int x = v;
#pragma unroll
    for (int o = 1; o < 64; o <<= 1) {
        int y = __shfl_up(x, o);
        if (lane >= o) x += y;
    }
    if (lane == 63) wtot[w] = x;
    __syncthreads();
    if (tid == 0) {
        int s = 0;
#pragma unroll
        for (int i = 0; i < 4; ++i) { int t = wtot[i]; wtot[i] = s; s += t; }
    }
    __syncthreads();
    return wtot[w] + x - v;
}

__global__ __launch_bounds__(256) void partial4_kernel(
    const int* __restrict__ deg4, int* __restrict__ part4)
{
    int g = blockIdx.y;
    int i = blockIdx.x * 256 + threadIdx.x;
    int v = (i < NPG) ? deg4[g * NPG + i] : 0;
#pragma unroll
    for (int o = 32; o > 0; o >>= 1) v += __shfl_xor(v, o);
    __shared__ int ws4[4];
    if ((threadIdx.x & 63) == 0) ws4[threadIdx.x >> 6] = v;
    __syncthreads();
    if (threadIdx.x == 0)
        part4[g * NPB + blockIdx.x] = ws4[0] + ws4[1] + ws4[2] + ws4[3];
}

__global__ __launch_bounds__(256) void scanp_kernel(
    const int* __restrict__ part4, int* __restrict__ pref4,
    int* __restrict__ offsets4)
{
    int g = blockIdx.y;
    int t = threadIdx.x;
    int v = (t < NPB) ? part4[g * NPB + t] : 0;
    int e = block_excl_scan(v, t);
    if (t < NPB) pref4[g * NPB + t] = e;
    if (t == 255) offsets4[(size_t)g * (NPG + 1) + NPG] = e + v;  // total
}

__global__ __launch_bounds__(256) void distribute_kernel(
    const int* __restrict__ deg4, const int* __restrict__ pref4,
    int* __restrict__ offsets4, int* __restrict__ cursor4)
{
    int g = blockIdx.y;
    int i = blockIdx.x * 256 + threadIdx.x;
    int v = (i < NPG) ? deg4[g * NPG + i] : 0;
    int e = block_excl_scan(v, threadIdx.x);
    if (i < NPG) {
        int off = pref4[g * NPB + blockIdx.x] + e;
        offsets4[(size_t)g * (NPG + 1) + i] = off;
        cursor4[g * NPG + i] = off;
    }
}

__global__ __launch_bounds__(256) void scatter4_kernel(
    const int* __restrict__ dst, const int* __restrict__ src,
    const int* __restrict__ tflag4, int* __restrict__ cursor4,
    int* __restrict__ perm4)
{
    int g = blockIdx.y;
    int e = blockIdx.x * 256 + threadIdx.x;
    if (e < EG) {
        int d = dst[(size_t)g * EG + e];
        if (tflag4[g * NPG + d]) {
            int pos = atomicAdd(&cursor4[g * NPG + d], 1);
            perm4[(size_t)g * EG + pos] = src[(size_t)g * EG + e];
        }
    }
}

// ---------------------------------------------------------------------------
// Aggregation: one block per target, one wave per head; z in bf16.
// 4 edge slots x 16 dim-lanes (4 dims = 8B bf16 per lane).
// ---------------------------------------------------------------------------
__global__ __launch_bounds__(256) void agg_kernel(
    const int* __restrict__ tgt, const int* __restrict__ offsets,
    const int* __restrict__ perm, const float* __restrict__ el,
    const float* __restrict__ er, const u16* __restrict__ zb,
    u16* __restrict__ metab)
{
    int t = blockIdx.x;
    int h = threadIdx.x >> 6;
    int lane = threadIdx.x & 63;
    int slot = lane >> 4, d4 = (lane & 15) * 4;
    int dstn = tgt[t];
    int start = offsets[dstn], end = offsets[dstn + 1];
    float erv = er[dstn * 4 + h];
    float mx = -INFINITY;
    for (int i = start + lane; i < end; i += 64) {
        float v = el[perm[i] * 4 + h] + erv;
        v = v > 0.f ? v : 0.2f * v;
        mx = fmaxf(mx, v);
    }
#pragma unroll
    for (int o = 32; o > 0; o >>= 1) mx = fmaxf(mx, __shfl_xor(mx, o));
    float4 accv = {0.f, 0.f, 0.f, 0.f};
    float denom = 0.f;
    for (int i = start + slot; i < end; i += 4) {
        int s = perm[i];
        float v = el[s * 4 + h] + erv;
        v = v > 0.f ? v : 0.2f * v;
        float ex = __expf(v - mx);
        denom += ex;
        uint2 w = *(const uint2*)&zb[(size_t)s * 256 + h * 64 + d4];
        float4 zv = up4(w.x, w.y);
        accv.x += ex * zv.x; accv.y += ex * zv.y;
        accv.z += ex * zv.z; accv.w += ex * zv.w;
    }
#pragma unroll
    for (int o = 16; o < 64; o <<= 1) {
        denom += __shfl_xor(denom, o);
        accv.x += __shfl_xor(accv.x, o);
        accv.y += __shfl_xor(accv.y, o);
        accv.z += __shfl_xor(accv.z, o);
        accv.w += __shfl_xor(accv.w, o);
    }
    if (slot == 0) {
        float inv = 1.f / (denom + 1e-9f);
        float4 o4;
        o4.x = accv.x * inv; o4.y = accv.y * inv;
        o4.z = accv.z * inv; o4.w = accv.w * inv;
        o4.x = o4.x > 0.f ? o4.x : expm1f(o4.x);
        o4.y = o4.y > 0.f ? o4.y : expm1f(o4.y);
        o4.z = o4.z > 0.f ? o4.z : expm1f(o4.z);
        o4.w = o4.w > 0.f ? o4.w : expm1f(o4.w);
        uint2 mw;
        mw.x = pk2(o4.x, o4.y); mw.y = pk2(o4.z, o4.w);
        *(uint2*)&metab[(size_t)t * 256 + h * 64 + d4] = mw;
    }
}

// ---------------------------------------------------------------------------
// Semantic logits: wsum[m] += sum_t tanh(meta[t]@W + b)@q
// N split in quarters (blockIdx.z); Bt quarter staged once; A direct bf16.
// ---------------------------------------------------------------------------
__global__ __launch_bounds__(256) void sem_kernel(
    const u16* __restrict__ metab, const float* __restrict__ semW,
    const float* __restrict__ semb, const float* __restrict__ semq,
    float* __restrict__ wsum)
{
    __shared__ short Bs[64 * 264];
    __shared__ float bsum;
    int m = blockIdx.y, nq = blockIdx.z;
    const u16* A = metab + (size_t)m * TT * 256;
    int tid = threadIdx.x, wv = tid >> 6, l = tid & 63, q = l >> 4, c = l & 15;
    if (tid == 0) bsum = 0.f;
    {
        int n = tid & 63, kh = tid >> 6;
        int gn = nq * 64 + n;
        for (int kp = 0; kp < 32; ++kp) {
            int k = kh * 64 + 2 * kp;
            float x = semW[(size_t)k * 256 + gn];
            float y = semW[(size_t)(k + 1) * 256 + gn];
            *(unsigned*)&Bs[n * 264 + k] = pk2(x, y);
        }
    }
    int rbase = blockIdx.x * 64;
    int row = rbase + wv * 16 + c;
    bool ok = row < TT;
    short8 af[8];
    const u16* Ap = A + (size_t)row * 256 + q * 8;
#pragma unroll
    for (int s = 0; s < 8; ++s)
        af[s] = ok ? *(const short8*)(Ap + 32 * s) : (short8)(short)0;
    __syncthreads();
    f32x4 acc[4];
#pragma unroll
    for (int i = 0; i < 4; ++i) acc[i] = (f32x4){0.f, 0.f, 0.f, 0.f};
#pragma unroll
    for (int s = 0; s < 8; ++s)
#pragma unroll
        for (int t4 = 0; t4 < 4; ++t4)
            acc[t4] = MFMA16(af[s],
                *(const short8*)&Bs[(t4 * 16 + c) * 264 + q * 8 + 32 * s], acc[t4]);
    float part = 0.f;
    int grl = rbase + wv * 16 + q * 4;
#pragma unroll
    for (int t4 = 0; t4 < 4; ++t4) {
        int col = nq * 64 + t4 * 16 + c;
        float bb = semb[col], qq = semq[col];
#pragma unroll
        for (int reg = 0; reg < 4; ++reg)
            if (grl + reg < TT) part += tanhf(acc[t4][reg] + bb) * qq;
    }
    for (int o = 32; o > 0; o >>= 1) part += __shfl_xor(part, o);
    if (l == 0) atomicAdd(&bsum, part);
    __syncthreads();
    if (tid == 0) atomicAdd(&wsum[m], bsum);
}

// ---------------------------------------------------------------------------
// Output: beta = softmax(wsum/T); s = b0*meta0+b1*meta1; out = s@foW + fob
// Bt staged once; A = blended bf16 metas loaded direct.
// ---------------------------------------------------------------------------
__global__ __launch_bounds__(256) void out_kernel(
    const u16* __restrict__ metab, const float* __restrict__ wsum,
    const float* __restrict__ foW, const float* __restrict__ fob,
    float* __restrict__ out)
{
    __shared__ short Bs[64 * 264];
    int tid = threadIdx.x, wv = tid >> 6, l = tid & 63, q = l >> 4, c = l & 15;
    float w0 = wsum[0] * (1.f / TT), w1 = wsum[1] * (1.f / TT);
    float mxv = fmaxf(w0, w1);
    float e0 = __expf(w0 - mxv), e1 = __expf(w1 - mxv);
    float inv = 1.f / (e0 + e1);
    float b0 = e0 * inv, b1 = e1 * inv;
    {
        int n = tid & 63, kh = tid >> 6;
        for (int kp = 0; kp < 32; ++kp) {
            int k = kh * 64 + 2 * kp;
            float x = foW[(size_t)k * 64 + n];
            float y = foW[(size_t)(k + 1) * 64 + n];
            *(unsigned*)&Bs[n * 264 + k] = pk2(x, y);
        }
    }
    int rbase = blockIdx.x * 64;
    int row = rbase + wv * 16 + c;
    bool ok = row < TT;
    const u16* Ap0 = metab + (size_t)row * 256 + q * 8;
    const u16* Ap1 = Ap0 + (size_t)TT * 256;
    short8 af[8];
#pragma unroll
    for (int s = 0; s < 8; ++s) {
        float4 v0 = {0.f, 0.f, 0.f, 0.f}, v1 = {0.f, 0.f, 0.f, 0.f};
        if (ok) {
            union { short8 s8; uint4 u; } ua, uc;
            ua.s8 = *(const short8*)(Ap0 + 32 * s);
            uc.s8 = *(const short8*)(Ap1 + 32 * s);
            float4 a0 = up4(ua.u.x, ua.u.y), a1 = up4(ua.u.z, ua.u.w);
            float4 c0 = up4(uc.u.x, uc.u.y), c1 = up4(uc.u.z, uc.u.w);
            v0.x = b0 * a0.x + b1 * c0.x; v0.y = b0 * a0.y + b1 * c0.y;
            v0.z = b0 * a0.z + b1 * c0.z; v0.w = b0 * a0.w + b1 * c0.w;
            v1.x = b0 * a1.x + b1 * c1.x; v1.y = b0 * a1.y + b1 * c1.y;
            v1.z = b0 * a1.z + b1 * c1.z; v1.w = b0 * a1.w + b1 * c1.w;
        }
        af[s] = cvt8(v0, v1);
    }
    __syncthreads();
    f32x4 acc[4];
#pragma unroll
    for (int i = 0; i < 4; ++i) acc[i] = (f32x4){0.f, 0.f, 0.f, 0.f};
#pragma unroll
    for (int s = 0; s < 8; ++s)
#pragma unroll
        for (int t4 = 0; t4 < 4; ++t4)
            acc[t4] = MFMA16(af[s],
                *(const short8*)&Bs[(t4 * 16 + c) * 264 + q * 8 + 32 * s], acc[t4]);
    int grl = rbase + wv * 16 + q * 4;
#pragma unroll
    for (int t4 = 0; t4 < 4; ++t4) {
        int col = t4 * 16 + c;
        float bv = fob[col];
#pragma unroll
        for (int reg = 0; reg < 4; ++reg) {
            int gr = grl + reg;
            if (gr < TT)
                out[(size_t)gr * 64 + col] = acc[t4][reg] + bv;
        }
    }
}

// ---------------------------------------------------------------------------
extern "C" void kernel_launch(void* const* d_in, const int* in_sizes, int n_in,
                              void* d_out, int out_size, void* d_ws, size_t ws_size,
                              hipStream_t stream)
{
    const float* f0    = (const float*)d_in[0];
    const float* f1    = (const float*)d_in[1];
    const float* fcW   = (const float*)d_in[2];
    const float* fcb   = (const float*)d_in[3];
    const float* gatW  = (const float*)d_in[4];
    const float* al    = (const float*)d_in[5];
    const float* ar    = (const float*)d_in[6];
    const float* semW  = (const float*)d_in[7];
    const float* semb  = (const float*)d_in[8];
    const float* semq  = (const float*)d_in[9];
    const float* foW   = (const float*)d_in[10];
    const float* fob   = (const float*)d_in[11];
    const int* type_idx = (const int*)d_in[12];
    const int* node_idx = (const int*)d_in[13];
    const int* edge_src = (const int*)d_in[14];
    const int* edge_dst = (const int*)d_in[15];
    const int* tgt_idx  = (const int*)d_in[16];
    float* out = (float*)d_out;

    char* ws = (char*)d_ws;
    size_t off = 0;
    auto alloc = [&](size_t bytes) -> void* {
        void* p = ws + off;
        off = (off + bytes + 255) & ~(size_t)255;
        return p;
    };
    u16*   tbf         = (u16*)alloc((size_t)NT * 64 * 2);
    u16*   zb          = (u16*)alloc((size_t)NPG * 256 * 2);
    float* el          = (float*)alloc((size_t)NPG * 4 * 4);
    float* er          = (float*)alloc((size_t)NPG * 4 * 4);
    u16*   metab       = (u16*)alloc((size_t)2 * TT * 256 * 2);
    float* wsum4       = (float*)alloc(64);
    int*   deg4        = (int*)alloc((size_t)4 * NPG * 4);
    int*   tflag4      = (int*)alloc((size_t)4 * NPG * 4);
    int*   offsets4    = (int*)alloc((size_t)4 * (NPG + 1) * 4);
    int*   cursor4     = (int*)alloc((size_t)4 * NPG * 4);
    int*   perm4       = (int*)alloc((size_t)4 * EG * 4);
    int*   part4       = (int*)alloc((size_t)4 * NPB * 4);
    int*   pref4       = (int*)alloc((size_t)4 * NPB * 4);

    const int eblocks = (EG + 255) / 256;
    const int tblocks = (TT + 255) / 256;

    // --- batched target-only CSR build for all 4 graphs ---
    hipMemsetAsync(deg4, 0, (size_t)4 * NPG * 4, stream);
    hipMemsetAsync(tflag4, 0, (size_t)4 * NPG * 4, stream);
    hipMemsetAsync(wsum4, 0, 16, stream);
    mark_kernel<<<dim3(tblocks, 4), 256, 0, stream>>>(tgt_idx, tflag4);
    count4_kernel<<<dim3(eblocks, 4), 256, 0, stream>>>(edge_dst, tflag4, deg4);
    partial4_kernel<<<dim3(NPB, 4), 256, 0, stream>>>(deg4, part4);
    scanp_kernel<<<dim3(1, 4), 256, 0, stream>>>(part4, pref4, offsets4);
    distribute_kernel<<<dim3(NPB, 4), 256, 0, stream>>>(deg4, pref4, offsets4,
                                                        cursor4);
    scatter4_kernel<<<dim3(eblocks, 4), 256, 0, stream>>>(edge_dst, edge_src,
                                                          tflag4, cursor4, perm4);

    fc_kernel<<<dim3(782, 2), 256, 0, stream>>>(f0, f1, fcW, fcb, type_idx, tbf);
    for (int b = 0; b < 2; ++b) {
        for (int m = 0; m < 2; ++m) {
            int g = b * 2 + m;
            z_kernel<<<782, 256, 0, stream>>>(
                tbf, node_idx + (size_t)g * NPG, gatW + (size_t)g * 64 * 256,
                al + (size_t)g * 256, ar + (size_t)g * 256, zb, el, er);
            agg_kernel<<<TT, 256, 0, stream>>>(
                tgt_idx + (size_t)g * TT, offsets4 + (size_t)g * (NPG + 1),
                perm4 + (size_t)g * EG, el, er, zb, metab + (size_t)m * TT * 256);
        }
        sem_kernel<<<dim3(313, 2, 4), 256, 0, stream>>>(
            metab, semW + (size_t)b * 256 * 256, semb + (size_t)b * 256,
            semq + (size_t)b * 256, wsum4 + b * 2);
        out_kernel<<<313, 256, 0, stream>>>(
            metab, wsum4 + b * 2, foW + (size_t)b * 256 * 64, fob + (size_t)b * 64,
            out + (size_t)b * TT * 64);
    }
}

// Round 6
// 621.361 us; speedup vs baseline: 2.8824x; 1.0389x over previous
//
#include <hip/hip_runtime.h>
#include <math.h>

#define NT     100000   // total nodes
#define NPT    50000    // nodes per type
#define NPG    50000    // nodes per metapath graph
#define EG     500000   // edges per graph
#define DD     256      // NH*HD
#define TT     20000    // targets per metapath
#define NPB    196      // scan partial blocks per graph (196*256 >= 50000)

typedef __attribute__((ext_vector_type(8))) short short8;   // 8 bf16 = 4 VGPRs
typedef __attribute__((ext_vector_type(4))) float f32x4;    // MFMA C/D
typedef unsigned short u16;

#define MFMA16(a, b, c) __builtin_amdgcn_mfma_f32_16x16x32_bf16((a), (b), (c), 0, 0, 0)

// RNE float->bf16 helpers
__device__ inline unsigned pk2(float x, float y) {
    unsigned a = __float_as_uint(x); a = (a + 0x7FFFu + ((a >> 16) & 1u)) >> 16;
    unsigned b = __float_as_uint(y); b = (b + 0x7FFFu + ((b >> 16) & 1u)) >> 16;
    return (a & 0xFFFFu) | (b << 16);
}
__device__ inline u16 pkb(float x) {
    unsigned a = __float_as_uint(x);
    return (u16)((a + 0x7FFFu + ((a >> 16) & 1u)) >> 16);
}
__device__ inline short8 cvt8(float4 a, float4 b) {
    union { int4 i; short8 s; } u;
    u.i = make_int4((int)pk2(a.x, a.y), (int)pk2(a.z, a.w),
                    (int)pk2(b.x, b.y), (int)pk2(b.z, b.w));
    return u.s;
}
__device__ inline float4 up4(unsigned lo, unsigned hi) {
    float4 r;
    r.x = __uint_as_float(lo << 16);
    r.y = __uint_as_float(lo & 0xFFFF0000u);
    r.z = __uint_as_float(hi << 16);
    r.w = __uint_as_float(hi & 0xFFFF0000u);
    return r;
}

// ---------------------------------------------------------------------------
// prep: convert all weights to bf16, transposing to [n][k] where needed.
// fcW [2][64n][256k] -> direct; gatW [4][64k][256n] -> [4][256n][64k];
// semW [2][256k][256n] -> [2][256n][256k]; foW [2][256k][64n] -> [2][64n][256k]
// ---------------------------------------------------------------------------
__global__ __launch_bounds__(256) void prep_kernel(
    const float* __restrict__ fcW, const float* __restrict__ gatW,
    const float* __restrict__ semW, const float* __restrict__ foW,
    u16* __restrict__ fcWb, u16* __restrict__ gatWb,
    u16* __restrict__ semWb, u16* __restrict__ foWb)
{
    int i = blockIdx.x * 256 + threadIdx.x;
    if (i < 32768) fcWb[i] = pkb(fcW[i]);
    if (i < 65536) {
        int g = i >> 14, rem = i & 16383, n = rem >> 6, k = rem & 63;
        gatWb[i] = pkb(gatW[g * 16384 + k * 256 + n]);
    }
    if (i < 131072) {
        int b = i >> 16, rem = i & 65535, n = rem >> 8, k = rem & 255;
        semWb[i] = pkb(semW[b * 65536 + k * 256 + n]);
    }
    if (i < 32768) {
        int b = i >> 14, rem = i & 16383, n = rem >> 8, k = rem & 255;
        foWb[i] = pkb(foW[b * 16384 + k * 64 + n]);
    }
}

// ---------------------------------------------------------------------------
// fc: tbf[type_idx[ty][r]] = bf16(features_ty @ fc_W[ty]^T + fc_b[ty])
// B: bf16 copy to LDS (8 indep chunks). A: load-8-then-convert, two rounds.
// ---------------------------------------------------------------------------
__global__ __launch_bounds__(256) void fc_kernel(
    const float* __restrict__ f0, const float* __restrict__ f1,
    const u16* __restrict__ fcWb, const float* __restrict__ fcb,
    const int* __restrict__ type_idx, u16* __restrict__ tbf)
{
    __shared__ short Bs[64 * 264];
    int ty = blockIdx.y;
    const float* feat = ty ? f1 : f0;
    const u16* W = fcWb + ty * 64 * 256;
    int tid = threadIdx.x, wv = tid >> 6, l = tid & 63, q = l >> 4, c = l & 15;
    short8 bv[8];
#pragma unroll
    for (int j = 0; j < 8; ++j)
        bv[j] = *(const short8*)&W[(tid + 256 * j) * 8];
    int rbase = blockIdx.x * 64;
    int row = rbase + wv * 16 + c;
    bool ok = row < NPT;
    const float* Ap = feat + (size_t)row * 256 + q * 8;
    short8 af[8];
#pragma unroll
    for (int half = 0; half < 2; ++half) {
        float4 va[8];
#pragma unroll
        for (int s = 0; s < 4; ++s) {
            va[2 * s] = (float4){0.f, 0.f, 0.f, 0.f};
            va[2 * s + 1] = (float4){0.f, 0.f, 0.f, 0.f};
        }
        if (ok) {
#pragma unroll
            for (int s = 0; s < 4; ++s) {
                int k = 32 * (half * 4 + s);
                va[2 * s] = *(const float4*)(Ap + k);
                va[2 * s + 1] = *(const float4*)(Ap + k + 4);
            }
        }
        if (half == 0) {
#pragma unroll
            for (int j = 0; j < 8; ++j) {
                int e = tid + 256 * j, r = e >> 5, kc = (e & 31) * 8;
                *(short8*)&Bs[r * 264 + kc] = bv[j];
            }
        }
#pragma unroll
        for (int s = 0; s < 4; ++s)
            af[half * 4 + s] = cvt8(va[2 * s], va[2 * s + 1]);
    }
    __syncthreads();
    f32x4 acc[4];
#pragma unroll
    for (int i = 0; i < 4; ++i) acc[i] = (f32x4){0.f, 0.f, 0.f, 0.f};
#pragma unroll
    for (int s = 0; s < 8; ++s)
#pragma unroll
        for (int t4 = 0; t4 < 4; ++t4)
            acc[t4] = MFMA16(af[s],
                *(const short8*)&Bs[(t4 * 16 + c) * 264 + q * 8 + 32 * s], acc[t4]);
    int grl = rbase + wv * 16 + q * 4;
#pragma unroll
    for (int t4 = 0; t4 < 4; ++t4) {
        int col = t4 * 16 + c;
        float bvv = fcb[ty * 64 + col];
#pragma unroll
        for (int reg = 0; reg < 4; ++reg) {
            int gr = grl + reg;
            if (gr < NPT) {
                int dest = type_idx[ty * NPT + gr];
                tbf[(size_t)dest * 64 + col] = pkb(acc[t4][reg] + bvv);
            }
        }
    }
}

// ---------------------------------------------------------------------------
// z = tbf[node_idx] @ gat_W (bf16 out), fused el/er epilogue (fp32).
// B: pre-transposed bf16 gatWb copy. A: gathered bf16 short8 direct.
// ---------------------------------------------------------------------------
__global__ __launch_bounds__(256) void z_kernel(
    const u16* __restrict__ tbf, const int* __restrict__ nidx,
    const u16* __restrict__ gatWb, const float* __restrict__ al,
    const float* __restrict__ ar, u16* __restrict__ zb,
    float* __restrict__ el, float* __restrict__ er)
{
    __shared__ short Bs[256 * 72];
    int tid = threadIdx.x, wv = tid >> 6, l = tid & 63, q = l >> 4, c = l & 15;
    short8 bv[8];
#pragma unroll
    for (int j = 0; j < 8; ++j)
        bv[j] = *(const short8*)&gatWb[(tid + 256 * j) * 8];
    int rbase = blockIdx.x * 64;
    int row = rbase + wv * 16 + c;
    bool ok = row < NPG;
    short8 af0 = (short8)(short)0, af1 = (short8)(short)0;
    if (ok) {
        int n = nidx[row];
        const u16* Ap = tbf + (size_t)n * 64 + q * 8;
        af0 = *(const short8*)(Ap);
        af1 = *(const short8*)(Ap + 32);
    }
#pragma unroll
    for (int j = 0; j < 8; ++j) {
        int e = tid + 256 * j, r = e >> 3, kc = (e & 7) * 8;
        *(short8*)&Bs[r * 72 + kc] = bv[j];
    }
    __syncthreads();
    f32x4 acc[16];
    const f32x4 zero = (f32x4){0.f, 0.f, 0.f, 0.f};
#pragma unroll
    for (int t16 = 0; t16 < 16; ++t16) {
        const short* Bp = &Bs[(t16 * 16 + c) * 72 + q * 8];
        acc[t16] = MFMA16(af0, *(const short8*)&Bp[0], zero);
        acc[t16] = MFMA16(af1, *(const short8*)&Bp[32], acc[t16]);
    }
    int grl = rbase + wv * 16 + q * 4;
#pragma unroll
    for (int t16 = 0; t16 < 16; ++t16)
#pragma unroll
        for (int reg = 0; reg < 4; ++reg) {
            int gr = grl + reg;
            if (gr < NPG)
                zb[(size_t)gr * 256 + t16 * 16 + c] = pkb(acc[t16][reg]);
        }
    float pl[4][4], pr[4][4];
#pragma unroll
    for (int reg = 0; reg < 4; ++reg)
#pragma unroll
        for (int h = 0; h < 4; ++h) { pl[reg][h] = 0.f; pr[reg][h] = 0.f; }
#pragma unroll
    for (int t16 = 0; t16 < 16; ++t16) {
        int col = t16 * 16 + c, h = t16 >> 2;
        float alv = al[col], arv = ar[col];
#pragma unroll
        for (int reg = 0; reg < 4; ++reg) {
            pl[reg][h] += acc[t16][reg] * alv;
            pr[reg][h] += acc[t16][reg] * arv;
        }
    }
#pragma unroll
    for (int o = 1; o < 16; o <<= 1)
#pragma unroll
        for (int reg = 0; reg < 4; ++reg)
#pragma unroll
            for (int h = 0; h < 4; ++h) {
                pl[reg][h] += __shfl_xor(pl[reg][h], o);
                pr[reg][h] += __shfl_xor(pr[reg][h], o);
            }
    if (c == 0) {
#pragma unroll
        for (int reg = 0; reg < 4; ++reg) {
            int gr = grl + reg;
            if (gr < NPG) {
                float4 vl = {pl[reg][0], pl[reg][1], pl[reg][2], pl[reg][3]};
                float4 vr = {pr[reg][0], pr[reg][1], pr[reg][2], pr[reg][3]};
                *(float4*)&el[gr * 4] = vl;
                *(float4*)&er[gr * 4] = vr;
            }
        }
    }
}

// ---------------------------------------------------------------------------
// CSR build over TARGET nodes only, batched over all 4 graphs.
// ---------------------------------------------------------------------------
__global__ __launch_bounds__(256) void mark_kernel(
    const int* __restrict__ tgt, int* __restrict__ tflag4)
{
    int g = blockIdx.y;
    int i = blockIdx.x * 256 + threadIdx.x;
    if (i < TT) tflag4[g * NPG + tgt[(size_t)g * TT + i]] = 1;
}

__global__ __launch_bounds__(256) void count4_kernel(
    const int* __restrict__ dst, const int* __restrict__ tflag4,
    int* __restrict__ deg4)
{
    int g = blockIdx.y;
    int e = blockIdx.x * 256 + threadIdx.x;
    if (e < EG) {
        int d = dst[(size_t)g * EG + e];
        if (tflag4[g * NPG + d]) atomicAdd(&deg4[g * NPG + d], 1);
    }
}

__device__ inline int block_excl_scan(int v, int tid) {
    __shared__ int wtot[4];
    int lane = tid & 63, w = tid >> 6;
    int x = v;
#pragma unroll
    for (int o = 1; o < 64; o <<= 1) {
        int y = __shfl_up(x, o);
        if (lane >= o) x += y;
    }
    if (lane == 63) wtot[w] = x;
    __syncthreads();
    if (tid == 0) {
        int s = 0;
#pragma unroll
        for (int i = 0; i < 4; ++i) { int t = wtot[i]; wtot[i] = s; s += t; }
    }
    __syncthreads();
    return wtot[w] + x - v;
}

__global__ __launch_bounds__(256) void partial4_kernel(
    const int* __restrict__ deg4, int* __restrict__ part4)
{
    int g = blockIdx.y;
    int i = blockIdx.x * 256 + threadIdx.x;
    int v = (i < NPG) ? deg4[g * NPG + i] : 0;
#pragma unroll
    for (int o = 32; o > 0; o >>= 1) v += __shfl_xor(v, o);
    __shared__ int ws4[4];
    if ((threadIdx.x & 63) == 0) ws4[threadIdx.x >> 6] = v;
    __syncthreads();
    if (threadIdx.x == 0)
        part4[g * NPB + blockIdx.x] = ws4[0] + ws4[1] + ws4[2] + ws4[3];
}

__global__ __launch_bounds__(256) void scanp_kernel(
    const int* __restrict__ part4, int* __restrict__ pref4,
    int* __restrict__ offsets4)
{
    int g = blockIdx.y;
    int t = threadIdx.x;
    int v = (t < NPB) ? part4[g * NPB + t] : 0;
    int e = block_excl_scan(v, t);
    if (t < NPB) pref4[g * NPB + t] = e;
    if (t == 255) offsets4[(size_t)g * (NPG + 1) + NPG] = e + v;  // total
}

__global__ __launch_bounds__(256) void distribute_kernel(
    const int* __restrict__ deg4, const int* __restrict__ pref4,
    int* __restrict__ offsets4, int* __restrict__ cursor4)
{
    int g = blockIdx.y;
    int i = blockIdx.x * 256 + threadIdx.x;
    int v = (i < NPG) ? deg4[g * NPG + i] : 0;
    int e = block_excl_scan(v, threadIdx.x);
    if (i < NPG) {
        int off = pref4[g * NPB + blockIdx.x] + e;
        offsets4[(size_t)g * (NPG + 1) + i] = off;
        cursor4[g * NPG + i] = off;
    }
}

__global__ __launch_bounds__(256) void scatter4_kernel(
    const int* __restrict__ dst, const int* __restrict__ src,
    const int* __restrict__ tflag4, int* __restrict__ cursor4,
    int* __restrict__ perm4)
{
    int g = blockIdx.y;
    int e = blockIdx.x * 256 + threadIdx.x;
    if (e < EG) {
        int d = dst[(size_t)g * EG + e];
        if (tflag4[g * NPG + d]) {
            int pos = atomicAdd(&cursor4[g * NPG + d], 1);
            perm4[(size_t)g * EG + pos] = src[(size_t)g * EG + e];
        }
    }
}

// ---------------------------------------------------------------------------
// Aggregation: one block per target, one wave per head; z in bf16.
// 8 edge slots x 8 dim-lanes (8 dims = 16B bf16 per lane).
// ---------------------------------------------------------------------------
__global__ __launch_bounds__(256) void agg_kernel(
    const int* __restrict__ tgt, const int* __restrict__ offsets,
    const int* __restrict__ perm, const float* __restrict__ el,
    const float* __restrict__ er, const u16* __restrict__ zb,
    u16* __restrict__ metab)
{
    int t = blockIdx.x;
    int h = threadIdx.x >> 6;
    int lane = threadIdx.x & 63;
    int slot = lane >> 3, d8 = (lane & 7) * 8;
    int dstn = tgt[t];
    int start = offsets[dstn], end = offsets[dstn + 1];
    float erv = er[dstn * 4 + h];
    float mx = -INFINITY;
    for (int i = start + lane; i < end; i += 64) {
        float v = el[perm[i] * 4 + h] + erv;
        v = v > 0.f ? v : 0.2f * v;
        mx = fmaxf(mx, v);
    }
#pragma unroll
    for (int o = 32; o > 0; o >>= 1) mx = fmaxf(mx, __shfl_xor(mx, o));
    float a[8];
#pragma unroll
    for (int j = 0; j < 8; ++j) a[j] = 0.f;
    float denom = 0.f;
    for (int i = start + slot; i < end; i += 8) {
        int s = perm[i];
        float v = el[s * 4 + h] + erv;
        v = v > 0.f ? v : 0.2f * v;
        float ex = __expf(v - mx);
        denom += ex;
        uint4 w = *(const uint4*)&zb[(size_t)s * 256 + h * 64 + d8];
        float4 z0 = up4(w.x, w.y), z1 = up4(w.z, w.w);
        a[0] += ex * z0.x; a[1] += ex * z0.y; a[2] += ex * z0.z; a[3] += ex * z0.w;
        a[4] += ex * z1.x; a[5] += ex * z1.y; a[6] += ex * z1.z; a[7] += ex * z1.w;
    }
#pragma unroll
    for (int o = 8; o < 64; o <<= 1) {
        denom += __shfl_xor(denom, o);
#pragma unroll
        for (int j = 0; j < 8; ++j) a[j] += __shfl_xor(a[j], o);
    }
    if (slot == 0) {
        float inv = 1.f / (denom + 1e-9f);
#pragma unroll
        for (int j = 0; j < 8; ++j) {
            float v = a[j] * inv;
            a[j] = v > 0.f ? v : expm1f(v);
        }
        uint4 mw;
        mw.x = pk2(a[0], a[1]); mw.y = pk2(a[2], a[3]);
        mw.z = pk2(a[4], a[5]); mw.w = pk2(a[6], a[7]);
        *(uint4*)&metab[(size_t)t * 256 + h * 64 + d8] = mw;
    }
}

// ---------------------------------------------------------------------------
// Semantic logits, batched over all 4 graphs (y=g) and N quarters (z=nq):
// wsum[g] += sum_t tanh(meta[g][t]@W[b] + b)@q
// ---------------------------------------------------------------------------
__global__ __launch_bounds__(256) void sem_kernel(
    const u16* __restrict__ metab4, const u16* __restrict__ semWb,
    const float* __restrict__ semb, const float* __restrict__ semq,
    float* __restrict__ wsum4)
{
    __shared__ short Bs[64 * 264];
    __shared__ float bsum;
    int g = blockIdx.y, b = g >> 1, nq = blockIdx.z;
    const u16* A = metab4 + (size_t)g * TT * 256;
    const u16* W = semWb + b * 65536 + nq * 64 * 256;
    int tid = threadIdx.x, wv = tid >> 6, l = tid & 63, q = l >> 4, c = l & 15;
    if (tid == 0) bsum = 0.f;
    short8 bv[8];
#pragma unroll
    for (int j = 0; j < 8; ++j)
        bv[j] = *(const short8*)&W[(tid + 256 * j) * 8];
    int rbase = blockIdx.x * 64;
    int row = rbase + wv * 16 + c;
    bool ok = row < TT;
    short8 af[8];
    const u16* Ap = A + (size_t)row * 256 + q * 8;
#pragma unroll
    for (int s = 0; s < 8; ++s)
        af[s] = ok ? *(const short8*)(Ap + 32 * s) : (short8)(short)0;
#pragma unroll
    for (int j = 0; j < 8; ++j) {
        int e = tid + 256 * j, r = e >> 5, kc = (e & 31) * 8;
        *(short8*)&Bs[r * 264 + kc] = bv[j];
    }
    __syncthreads();
    f32x4 acc[4];
#pragma unroll
    for (int i = 0; i < 4; ++i) acc[i] = (f32x4){0.f, 0.f, 0.f, 0.f};
#pragma unroll
    for (int s = 0; s < 8; ++s)
#pragma unroll
        for (int t4 = 0; t4 < 4; ++t4)
            acc[t4] = MFMA16(af[s],
                *(const short8*)&Bs[(t4 * 16 + c) * 264 + q * 8 + 32 * s], acc[t4]);
    float part = 0.f;
    int grl = rbase + wv * 16 + q * 4;
#pragma unroll
    for (int t4 = 0; t4 < 4; ++t4) {
        int col = nq * 64 + t4 * 16 + c;
        float bb = semb[b * 256 + col], qq = semq[b * 256 + col];
#pragma unroll
        for (int reg = 0; reg < 4; ++reg)
            if (grl + reg < TT) part += tanhf(acc[t4][reg] + bb) * qq;
    }
    for (int o = 32; o > 0; o >>= 1) part += __shfl_xor(part, o);
    if (l == 0) atomicAdd(&bsum, part);
    __syncthreads();
    if (tid == 0) atomicAdd(&wsum4[g], bsum);
}

// ---------------------------------------------------------------------------
// Output, batched over branches (y=b): beta = softmax(wsum[b*2..]/T);
// s = b0*meta0+b1*meta1; out = s@foW + fob
// ---------------------------------------------------------------------------
__global__ __launch_bounds__(256) void out_kernel(
    const u16* __restrict__ metab4, const float* __restrict__ wsum4,
    const u16* __restrict__ foWb, const float* __restrict__ fob,
    float* __restrict__ out)
{
    __shared__ short Bs[64 * 264];
    int b = blockIdx.y;
    int tid = threadIdx.x, wv = tid >> 6, l = tid & 63, q = l >> 4, c = l & 15;
    float w0 = wsum4[b * 2] * (1.f / TT), w1 = wsum4[b * 2 + 1] * (1.f / TT);
    float mxv = fmaxf(w0, w1);
    float e0 = __expf(w0 - mxv), e1 = __expf(w1 - mxv);
    float inv = 1.f / (e0 + e1);
    float b0 = e0 * inv, b1 = e1 * inv;
    const u16* W = foWb + b * 16384;
    short8 bv[8];
#pragma unroll
    for (int j = 0; j < 8; ++j)
        bv[j] = *(const short8*)&W[(tid + 256 * j) * 8];
    int rbase = blockIdx.x * 64;
    int row = rbase + wv * 16 + c;
    bool ok = row < TT;
    const u16* Ap0 = metab4 + (size_t)(b * 2) * TT * 256 + (size_t)row * 256 + q * 8;
    const u16* Ap1 = Ap0 + (size_t)TT * 256;
    short8 af[8];
#pragma unroll
    for (int half = 0; half < 2; ++half) {
        union { short8 s8; uint4 u; } ua[4], uc[4];
#pragma unroll
        for (int s = 0; s < 4; ++s) {
            int ss = half * 4 + s;
            ua[s].s8 = ok ? *(const short8*)(Ap0 + 32 * ss) : (short8)(short)0;
            uc[s].s8 = ok ? *(const short8*)(Ap1 + 32 * ss) : (short8)(short)0;
        }
        if (half == 0) {
#pragma unroll
            for (int j = 0; j < 8; ++j) {
                int e = tid + 256 * j, r = e >> 5, kc = (e & 31) * 8;
                *(short8*)&Bs[r * 264 + kc] = bv[j];
            }
        }
#pragma unroll
        for (int s = 0; s < 4; ++s) {
            float4 a0 = up4(ua[s].u.x, ua[s].u.y), a1 = up4(ua[s].u.z, ua[s].u.w);
            float4 c0 = up4(uc[s].u.x, uc[s].u.y), c1 = up4(uc[s].u.z, uc[s].u.w);
            float4 v0, v1;
            v0.x = b0 * a0.x + b1 * c0.x; v0.y = b0 * a0.y + b1 * c0.y;
            v0.z = b0 * a0.z + b1 * c0.z; v0.w = b0 * a0.w + b1 * c0.w;
            v1.x = b0 * a1.x + b1 * c1.x; v1.y = b0 * a1.y + b1 * c1.y;
            v1.z = b0 * a1.z + b1 * c1.z; v1.w = b0 * a1.w + b1 * c1.w;
            af[half * 4 + s] = cvt8(v0, v1);
        }
    }
    __syncthreads();
    f32x4 acc[4];
#pragma unroll
    for (int i = 0; i < 4; ++i) acc[i] = (f32x4){0.f, 0.f, 0.f, 0.f};
#pragma unroll
    for (int s = 0; s < 8; ++s)
#pragma unroll
        for (int t4 = 0; t4 < 4; ++t4)
            acc[t4] = MFMA16(af[s],
                *(const short8*)&Bs[(t4 * 16 + c) * 264 + q * 8 + 32 * s], acc[t4]);
    int grl = rbase + wv * 16 + q * 4;
#pragma unroll
    for (int t4 = 0; t4 < 4; ++t4) {
        int col = t4 * 16 + c;
        float bvv = fob[b * 64 + col];
#pragma unroll
        for (int reg = 0; reg < 4; ++reg) {
            int gr = grl + reg;
            if (gr < TT)
                out[(size_t)b * TT * 64 + (size_t)gr * 64 + col] = acc[t4][reg] + bvv;
        }
    }
}

// ---------------------------------------------------------------------------
extern "C" void kernel_launch(void* const* d_in, const int* in_sizes, int n_in,
                              void* d_out, int out_size, void* d_ws, size_t ws_size,
                              hipStream_t stream)
{
    const float* f0    = (const float*)d_in[0];
    const float* f1    = (const float*)d_in[1];
    const float* fcW   = (const float*)d_in[2];
    const float* fcb   = (const float*)d_in[3];
    const float* gatW  = (const float*)d_in[4];
    const float* al    = (const float*)d_in[5];
    const float* ar    = (const float*)d_in[6];
    const float* semW  = (const float*)d_in[7];
    const float* semb  = (const float*)d_in[8];
    const float* semq  = (const float*)d_in[9];
    const float* foW   = (const float*)d_in[10];
    const float* fob   = (const float*)d_in[11];
    const int* type_idx = (const int*)d_in[12];
    const int* node_idx = (const int*)d_in[13];
    const int* edge_src = (const int*)d_in[14];
    const int* edge_dst = (const int*)d_in[15];
    const int* tgt_idx  = (const int*)d_in[16];
    float* out = (float*)d_out;

    char* ws = (char*)d_ws;
    size_t off = 0;
    auto alloc = [&](size_t bytes) -> void* {
        void* p = ws + off;
        off = (off + bytes + 255) & ~(size_t)255;
        return p;
    };
    u16*   tbf         = (u16*)alloc((size_t)NT * 64 * 2);
    u16*   zb          = (u16*)alloc((size_t)NPG * 256 * 2);
    float* el          = (float*)alloc((size_t)NPG * 4 * 4);
    float* er          = (float*)alloc((size_t)NPG * 4 * 4);
    u16*   metab4      = (u16*)alloc((size_t)4 * TT * 256 * 2);
    float* wsum4       = (float*)alloc(64);
    u16*   fcWb        = (u16*)alloc(32768 * 2);
    u16*   gatWb       = (u16*)alloc(65536 * 2);
    u16*   semWb       = (u16*)alloc(131072 * 2);
    u16*   foWb        = (u16*)alloc(32768 * 2);
    int*   deg4        = (int*)alloc((size_t)4 * NPG * 4);
    int*   tflag4      = (int*)alloc((size_t)4 * NPG * 4);
    int*   offsets4    = (int*)alloc((size_t)4 * (NPG + 1) * 4);
    int*   cursor4     = (int*)alloc((size_t)4 * NPG * 4);
    int*   perm4       = (int*)alloc((size_t)4 * EG * 4);
    int*   part4       = (int*)alloc((size_t)4 * NPB * 4);
    int*   pref4       = (int*)alloc((size_t)4 * NPB * 4);

    const int eblocks = (EG + 255) / 256;
    const int tblocks = (TT + 255) / 256;

    prep_kernel<<<512, 256, 0, stream>>>(fcW, gatW, semW, foW,
                                         fcWb, gatWb, semWb, foWb);

    // --- batched target-only CSR build for all 4 graphs ---
    hipMemsetAsync(deg4, 0, (size_t)4 * NPG * 4, stream);
    hipMemsetAsync(tflag4, 0, (size_t)4 * NPG * 4, stream);
    hipMemsetAsync(wsum4, 0, 16, stream);
    mark_kernel<<<dim3(tblocks, 4), 256, 0, stream>>>(tgt_idx, tflag4);
    count4_kernel<<<dim3(eblocks, 4), 256, 0, stream>>>(edge_dst, tflag4, deg4);
    partial4_kernel<<<dim3(NPB, 4), 256, 0, stream>>>(deg4, part4);
    scanp_kernel<<<dim3(1, 4), 256, 0, stream>>>(part4, pref4, offsets4);
    distribute_kernel<<<dim3(NPB, 4), 256, 0, stream>>>(deg4, pref4, offsets4,
                                                        cursor4);
    scatter4_kernel<<<dim3(eblocks, 4), 256, 0, stream>>>(edge_dst, edge_src,
                                                          tflag4, cursor4, perm4);

    fc_kernel<<<dim3(782, 2), 256, 0, stream>>>(f0, f1, fcWb, fcb, type_idx, tbf);
    for (int g = 0; g < 4; ++g) {
        z_kernel<<<782, 256, 0, stream>>>(
            tbf, node_idx + (size_t)g * NPG, gatWb + (size_t)g * 16384,
            al + (size_t)g * 256, ar + (size_t)g * 256, zb, el, er);
        agg_kernel<<<TT, 256, 0, stream>>>(
            tgt_idx + (size_t)g * TT, offsets4 + (size_t)g * (NPG + 1),
            perm4 + (size_t)g * EG, el, er, zb, metab4 + (size_t)g * TT * 256);
    }
    sem_kernel<<<dim3(313, 4, 4), 256, 0, stream>>>(metab4, semWb, semb, semq,
                                                    wsum4);
    out_kernel<<<dim3(313, 2), 256, 0, stream>>>(metab4, wsum4, foWb, fob, out);
}

// Round 7
// 561.943 us; speedup vs baseline: 3.1872x; 1.1057x over previous
//
#include <hip/hip_runtime.h>
#include <math.h>

#define NT     100000   // total nodes
#define NPT    50000    // nodes per type
#define NPG    50000    // nodes per metapath graph
#define EG     500000   // edges per graph
#define DD     256      // NH*HD
#define TT     20000    // targets per metapath
#define NPB    196      // scan partial blocks per graph (196*256 >= 50000)

typedef __attribute__((ext_vector_type(8))) short short8;   // 8 bf16 = 4 VGPRs
typedef __attribute__((ext_vector_type(4))) float f32x4;    // MFMA C/D
typedef unsigned short u16;

#define MFMA16(a, b, c) __builtin_amdgcn_mfma_f32_16x16x32_bf16((a), (b), (c), 0, 0, 0)

// RNE float->bf16 helpers
__device__ inline unsigned pk2(float x, float y) {
    unsigned a = __float_as_uint(x); a = (a + 0x7FFFu + ((a >> 16) & 1u)) >> 16;
    unsigned b = __float_as_uint(y); b = (b + 0x7FFFu + ((b >> 16) & 1u)) >> 16;
    return (a & 0xFFFFu) | (b << 16);
}
__device__ inline u16 pkb(float x) {
    unsigned a = __float_as_uint(x);
    return (u16)((a + 0x7FFFu + ((a >> 16) & 1u)) >> 16);
}
__device__ inline short8 cvt8(float4 a, float4 b) {
    union { int4 i; short8 s; } u;
    u.i = make_int4((int)pk2(a.x, a.y), (int)pk2(a.z, a.w),
                    (int)pk2(b.x, b.y), (int)pk2(b.z, b.w));
    return u.s;
}
__device__ inline float4 up4(unsigned lo, unsigned hi) {
    float4 r;
    r.x = __uint_as_float(lo << 16);
    r.y = __uint_as_float(lo & 0xFFFF0000u);
    r.z = __uint_as_float(hi << 16);
    r.w = __uint_as_float(hi & 0xFFFF0000u);
    return r;
}
// fast tanh: 1 - 2/(e^{2x}+1) via v_exp_f32 + v_rcp_f32 (rel err ~1e-6)
__device__ inline float ftanh(float x) {
    float e = __expf(2.f * x);
    return 1.f - 2.f * __builtin_amdgcn_rcpf(e + 1.f);
}

// ---------------------------------------------------------------------------
// prep: convert all weights to bf16, transposing to [n][k] where needed.
// ---------------------------------------------------------------------------
__global__ __launch_bounds__(256) void prep_kernel(
    const float* __restrict__ fcW, const float* __restrict__ gatW,
    const float* __restrict__ semW, const float* __restrict__ foW,
    u16* __restrict__ fcWb, u16* __restrict__ gatWb,
    u16* __restrict__ semWb, u16* __restrict__ foWb)
{
    int i = blockIdx.x * 256 + threadIdx.x;
    if (i < 32768) fcWb[i] = pkb(fcW[i]);
    if (i < 65536) {
        int g = i >> 14, rem = i & 16383, n = rem >> 6, k = rem & 63;
        gatWb[i] = pkb(gatW[g * 16384 + k * 256 + n]);
    }
    if (i < 131072) {
        int b = i >> 16, rem = i & 65535, n = rem >> 8, k = rem & 255;
        semWb[i] = pkb(semW[b * 65536 + k * 256 + n]);
    }
    if (i < 32768) {
        int b = i >> 14, rem = i & 16383, n = rem >> 8, k = rem & 255;
        foWb[i] = pkb(foW[b * 16384 + k * 64 + n]);
    }
}

// ---------------------------------------------------------------------------
// fc: tbf[type_idx[ty][r]] = bf16(features_ty @ fc_W[ty]^T + fc_b[ty])
// ---------------------------------------------------------------------------
__global__ __launch_bounds__(256) void fc_kernel(
    const float* __restrict__ f0, const float* __restrict__ f1,
    const u16* __restrict__ fcWb, const float* __restrict__ fcb,
    const int* __restrict__ type_idx, u16* __restrict__ tbf)
{
    __shared__ short Bs[64 * 264];
    int ty = blockIdx.y;
    const float* feat = ty ? f1 : f0;
    const u16* W = fcWb + ty * 64 * 256;
    int tid = threadIdx.x, wv = tid >> 6, l = tid & 63, q = l >> 4, c = l & 15;
    short8 bv[8];
#pragma unroll
    for (int j = 0; j < 8; ++j)
        bv[j] = *(const short8*)&W[(tid + 256 * j) * 8];
    int rbase = blockIdx.x * 64;
    int row = rbase + wv * 16 + c;
    bool ok = row < NPT;
    const float* Ap = feat + (size_t)row * 256 + q * 8;
    short8 af[8];
#pragma unroll
    for (int half = 0; half < 2; ++half) {
        float4 va[8];
#pragma unroll
        for (int s = 0; s < 4; ++s) {
            va[2 * s] = (float4){0.f, 0.f, 0.f, 0.f};
            va[2 * s + 1] = (float4){0.f, 0.f, 0.f, 0.f};
        }
        if (ok) {
#pragma unroll
            for (int s = 0; s < 4; ++s) {
                int k = 32 * (half * 4 + s);
                va[2 * s] = *(const float4*)(Ap + k);
                va[2 * s + 1] = *(const float4*)(Ap + k + 4);
            }
        }
        if (half == 0) {
#pragma unroll
            for (int j = 0; j < 8; ++j) {
                int e = tid + 256 * j, r = e >> 5, kc = (e & 31) * 8;
                *(short8*)&Bs[r * 264 + kc] = bv[j];
            }
        }
#pragma unroll
        for (int s = 0; s < 4; ++s)
            af[half * 4 + s] = cvt8(va[2 * s], va[2 * s + 1]);
    }
    __syncthreads();
    f32x4 acc[4];
#pragma unroll
    for (int i = 0; i < 4; ++i) acc[i] = (f32x4){0.f, 0.f, 0.f, 0.f};
#pragma unroll
    for (int s = 0; s < 8; ++s)
#pragma unroll
        for (int t4 = 0; t4 < 4; ++t4)
            acc[t4] = MFMA16(af[s],
                *(const short8*)&Bs[(t4 * 16 + c) * 264 + q * 8 + 32 * s], acc[t4]);
    int grl = rbase + wv * 16 + q * 4;
#pragma unroll
    for (int t4 = 0; t4 < 4; ++t4) {
        int col = t4 * 16 + c;
        float bvv = fcb[ty * 64 + col];
#pragma unroll
        for (int reg = 0; reg < 4; ++reg) {
            int gr = grl + reg;
            if (gr < NPT) {
                int dest = type_idx[ty * NPT + gr];
                tbf[(size_t)dest * 64 + col] = pkb(acc[t4][reg] + bvv);
            }
        }
    }
}

// ---------------------------------------------------------------------------
// z = tbf[node_idx] @ gat_W (bf16 out), fused el/er epilogue (fp32).
// ---------------------------------------------------------------------------
__global__ __launch_bounds__(256) void z_kernel(
    const u16* __restrict__ tbf, const int* __restrict__ nidx,
    const u16* __restrict__ gatWb, const float* __restrict__ al,
    const float* __restrict__ ar, u16* __restrict__ zb,
    float* __restrict__ el, float* __restrict__ er)
{
    __shared__ short Bs[256 * 72];
    int tid = threadIdx.x, wv = tid >> 6, l = tid & 63, q = l >> 4, c = l & 15;
    short8 bv[8];
#pragma unroll
    for (int j = 0; j < 8; ++j)
        bv[j] = *(const short8*)&gatWb[(tid + 256 * j) * 8];
    int rbase = blockIdx.x * 64;
    int row = rbase + wv * 16 + c;
    bool ok = row < NPG;
    short8 af0 = (short8)(short)0, af1 = (short8)(short)0;
    if (ok) {
        int n = nidx[row];
        const u16* Ap = tbf + (size_t)n * 64 + q * 8;
        af0 = *(const short8*)(Ap);
        af1 = *(const short8*)(Ap + 32);
    }
#pragma unroll
    for (int j = 0; j < 8; ++j) {
        int e = tid + 256 * j, r = e >> 3, kc = (e & 7) * 8;
        *(short8*)&Bs[r * 72 + kc] = bv[j];
    }
    __syncthreads();
    f32x4 acc[16];
    const f32x4 zero = (f32x4){0.f, 0.f, 0.f, 0.f};
#pragma unroll
    for (int t16 = 0; t16 < 16; ++t16) {
        const short* Bp = &Bs[(t16 * 16 + c) * 72 + q * 8];
        acc[t16] = MFMA16(af0, *(const short8*)&Bp[0], zero);
        acc[t16] = MFMA16(af1, *(const short8*)&Bp[32], acc[t16]);
    }
    int grl = rbase + wv * 16 + q * 4;
#pragma unroll
    for (int t16 = 0; t16 < 16; ++t16)
#pragma unroll
        for (int reg = 0; reg < 4; ++reg) {
            int gr = grl + reg;
            if (gr < NPG)
                zb[(size_t)gr * 256 + t16 * 16 + c] = pkb(acc[t16][reg]);
        }
    float pl[4][4], pr[4][4];
#pragma unroll
    for (int reg = 0; reg < 4; ++reg)
#pragma unroll
        for (int h = 0; h < 4; ++h) { pl[reg][h] = 0.f; pr[reg][h] = 0.f; }
#pragma unroll
    for (int t16 = 0; t16 < 16; ++t16) {
        int col = t16 * 16 + c, h = t16 >> 2;
        float alv = al[col], arv = ar[col];
#pragma unroll
        for (int reg = 0; reg < 4; ++reg) {
            pl[reg][h] += acc[t16][reg] * alv;
            pr[reg][h] += acc[t16][reg] * arv;
        }
    }
#pragma unroll
    for (int o = 1; o < 16; o <<= 1)
#pragma unroll
        for (int reg = 0; reg < 4; ++reg)
#pragma unroll
            for (int h = 0; h < 4; ++h) {
                pl[reg][h] += __shfl_xor(pl[reg][h], o);
                pr[reg][h] += __shfl_xor(pr[reg][h], o);
            }
    if (c == 0) {
#pragma unroll
        for (int reg = 0; reg < 4; ++reg) {
            int gr = grl + reg;
            if (gr < NPG) {
                float4 vl = {pl[reg][0], pl[reg][1], pl[reg][2], pl[reg][3]};
                float4 vr = {pr[reg][0], pr[reg][1], pr[reg][2], pr[reg][3]};
                *(float4*)&el[gr * 4] = vl;
                *(float4*)&er[gr * 4] = vr;
            }
        }
    }
}

// ---------------------------------------------------------------------------
// CSR build over TARGET nodes only, batched over all 4 graphs.
// ---------------------------------------------------------------------------
__global__ __launch_bounds__(256) void mark_kernel(
    const int* __restrict__ tgt, int* __restrict__ tflag4)
{
    int g = blockIdx.y;
    int i = blockIdx.x * 256 + threadIdx.x;
    if (i < TT) tflag4[g * NPG + tgt[(size_t)g * TT + i]] = 1;
}

__global__ __launch_bounds__(256) void count4_kernel(
    const int* __restrict__ dst, const int* __restrict__ tflag4,
    int* __restrict__ deg4)
{
    int g = blockIdx.y;
    int e = blockIdx.x * 256 + threadIdx.x;
    if (e < EG) {
        int d = dst[(size_t)g * EG + e];
        if (tflag4[g * NPG + d]) atomicAdd(&deg4[g * NPG + d], 1);
    }
}

__device__ inline int block_excl_scan(int v, int tid) {
    __shared__ int wtot[4];
    int lane = tid & 63, w = tid >> 6;
    int x = v;
#pragma unroll
    for (int o = 1; o < 64; o <<= 1) {
        int y = __shfl_up(x, o);
        if (lane >= o) x += y;
    }
    if (lane == 63) wtot[w] = x;
    __syncthreads();
    if (tid == 0) {
        int s = 0;
#pragma unroll
        for (int i = 0; i < 4; ++i) { int t = wtot[i]; wtot[i] = s; s += t; }
    }
    __syncthreads();
    return wtot[w] + x - v;
}

__global__ __launch_bounds__(256) void partial4_kernel(
    const int* __restrict__ deg4, int* __restrict__ part4)
{
    int g = blockIdx.y;
    int i = blockIdx.x * 256 + threadIdx.x;
    int v = (i < NPG) ? deg4[g * NPG + i] : 0;
#pragma unroll
    for (int o = 32; o > 0; o >>= 1) v += __shfl_xor(v, o);
    __shared__ int ws4[4];
    if ((threadIdx.x & 63) == 0) ws4[threadIdx.x >> 6] = v;
    __syncthreads();
    if (threadIdx.x == 0)
        part4[g * NPB + blockIdx.x] = ws4[0] + ws4[1] + ws4[2] + ws4[3];
}

__global__ __launch_bounds__(256) void scanp_kernel(
    const int* __restrict__ part4, int* __restrict__ pref4,
    int* __restrict__ offsets4)
{
    int g = blockIdx.y;
    int t = threadIdx.x;
    int v = (t < NPB) ? part4[g * NPB + t] : 0;
    int e = block_excl_scan(v, t);
    if (t < NPB) pref4[g * NPB + t] = e;
    if (t == 255) offsets4[(size_t)g * (NPG + 1) + NPG] = e + v;  // total
}

__global__ __launch_bounds__(256) void distribute_kernel(
    const int* __restrict__ deg4, const int* __restrict__ pref4,
    int* __restrict__ offsets4, int* __restrict__ cursor4)
{
    int g = blockIdx.y;
    int i = blockIdx.x * 256 + threadIdx.x;
    int v = (i < NPG) ? deg4[g * NPG + i] : 0;
    int e = block_excl_scan(v, threadIdx.x);
    if (i < NPG) {
        int off = pref4[g * NPB + blockIdx.x] + e;
        offsets4[(size_t)g * (NPG + 1) + i] = off;
        cursor4[g * NPG + i] = off;
    }
}

__global__ __launch_bounds__(256) void scatter4_kernel(
    const int* __restrict__ dst, const int* __restrict__ src,
    const int* __restrict__ tflag4, int* __restrict__ cursor4,
    int* __restrict__ perm4)
{
    int g = blockIdx.y;
    int e = blockIdx.x * 256 + threadIdx.x;
    if (e < EG) {
        int d = dst[(size_t)g * EG + e];
        if (tflag4[g * NPG + d]) {
            int pos = atomicAdd(&cursor4[g * NPG + d], 1);
            perm4[(size_t)g * EG + pos] = src[(size_t)g * EG + e];
        }
    }
}

// ---------------------------------------------------------------------------
// Aggregation: one block per target, one wave per head; z in bf16.
// 8 edge slots x 8 dim-lanes (8 dims = 16B bf16 per lane).
// ---------------------------------------------------------------------------
__global__ __launch_bounds__(256) void agg_kernel(
    const int* __restrict__ tgt, const int* __restrict__ offsets,
    const int* __restrict__ perm, const float* __restrict__ el,
    const float* __restrict__ er, const u16* __restrict__ zb,
    u16* __restrict__ metab)
{
    int t = blockIdx.x;
    int h = threadIdx.x >> 6;
    int lane = threadIdx.x & 63;
    int slot = lane >> 3, d8 = (lane & 7) * 8;
    int dstn = tgt[t];
    int start = offsets[dstn], end = offsets[dstn + 1];
    float erv = er[dstn * 4 + h];
    float mx = -INFINITY;
    for (int i = start + lane; i < end; i += 64) {
        float v = el[perm[i] * 4 + h] + erv;
        v = v > 0.f ? v : 0.2f * v;
        mx = fmaxf(mx, v);
    }
#pragma unroll
    for (int o = 32; o > 0; o >>= 1) mx = fmaxf(mx, __shfl_xor(mx, o));
    float a[8];
#pragma unroll
    for (int j = 0; j < 8; ++j) a[j] = 0.f;
    float denom = 0.f;
    for (int i = start + slot; i < end; i += 8) {
        int s = perm[i];
        float v = el[s * 4 + h] + erv;
        v = v > 0.f ? v : 0.2f * v;
        float ex = __expf(v - mx);
        denom += ex;
        uint4 w = *(const uint4*)&zb[(size_t)s * 256 + h * 64 + d8];
        float4 z0 = up4(w.x, w.y), z1 = up4(w.z, w.w);
        a[0] += ex * z0.x; a[1] += ex * z0.y; a[2] += ex * z0.z; a[3] += ex * z0.w;
        a[4] += ex * z1.x; a[5] += ex * z1.y; a[6] += ex * z1.z; a[7] += ex * z1.w;
    }
#pragma unroll
    for (int o = 8; o < 64; o <<= 1) {
        denom += __shfl_xor(denom, o);
#pragma unroll
        for (int j = 0; j < 8; ++j) a[j] += __shfl_xor(a[j], o);
    }
    if (slot == 0) {
        float inv = __builtin_amdgcn_rcpf(denom + 1e-9f);
#pragma unroll
        for (int j = 0; j < 8; ++j) {
            float v = a[j] * inv;
            a[j] = v > 0.f ? v : (__expf(v) - 1.f);
        }
        uint4 mw;
        mw.x = pk2(a[0], a[1]); mw.y = pk2(a[2], a[3]);
        mw.z = pk2(a[4], a[5]); mw.w = pk2(a[6], a[7]);
        *(uint4*)&metab[(size_t)t * 256 + h * 64 + d8] = mw;
    }
}

// ---------------------------------------------------------------------------
// Semantic logits, batched over all 4 graphs (y=g). N-quarters looped
// IN-BLOCK with A-fragments register-resident (A fetched once from HBM).
// wsum[g] += sum_t tanh(meta[g][t]@W[b] + b)@q
// ---------------------------------------------------------------------------
__global__ __launch_bounds__(256) void sem_kernel(
    const u16* __restrict__ metab4, const u16* __restrict__ semWb,
    const float* __restrict__ semb, const float* __restrict__ semq,
    float* __restrict__ wsum4)
{
    __shared__ short Bs[64 * 264];
    __shared__ float bsum;
    int g = blockIdx.y, b = g >> 1;
    const u16* A = metab4 + (size_t)g * TT * 256;
    int tid = threadIdx.x, wv = tid >> 6, l = tid & 63, q = l >> 4, c = l & 15;
    if (tid == 0) bsum = 0.f;
    int rbase = blockIdx.x * 64;
    int row = rbase + wv * 16 + c;
    bool ok = row < TT;
    short8 af[8];
    const u16* Ap = A + (size_t)row * 256 + q * 8;
#pragma unroll
    for (int s = 0; s < 8; ++s)
        af[s] = ok ? *(const short8*)(Ap + 32 * s) : (short8)(short)0;
    float part = 0.f;
    int grl = rbase + wv * 16 + q * 4;
    for (int nq = 0; nq < 4; ++nq) {
        const u16* W = semWb + b * 65536 + nq * 16384;
        short8 bv[8];
#pragma unroll
        for (int j = 0; j < 8; ++j)
            bv[j] = *(const short8*)&W[(tid + 256 * j) * 8];
        __syncthreads();          // previous quarter's Bs reads done
#pragma unroll
        for (int j = 0; j < 8; ++j) {
            int e = tid + 256 * j, r = e >> 5, kc = (e & 31) * 8;
            *(short8*)&Bs[r * 264 + kc] = bv[j];
        }
        __syncthreads();
        f32x4 acc[4];
#pragma unroll
        for (int i = 0; i < 4; ++i) acc[i] = (f32x4){0.f, 0.f, 0.f, 0.f};
#pragma unroll
        for (int s = 0; s < 8; ++s)
#pragma unroll
            for (int t4 = 0; t4 < 4; ++t4)
                acc[t4] = MFMA16(af[s],
                    *(const short8*)&Bs[(t4 * 16 + c) * 264 + q * 8 + 32 * s], acc[t4]);
#pragma unroll
        for (int t4 = 0; t4 < 4; ++t4) {
            int col = nq * 64 + t4 * 16 + c;
            float bb = semb[b * 256 + col], qq = semq[b * 256 + col];
#pragma unroll
            for (int reg = 0; reg < 4; ++reg)
                if (grl + reg < TT) part += ftanh(acc[t4][reg] + bb) * qq;
        }
    }
    for (int o = 32; o > 0; o >>= 1) part += __shfl_xor(part, o);
    if (l == 0) atomicAdd(&bsum, part);
    __syncthreads();
    if (tid == 0) atomicAdd(&wsum4[g], bsum);
}

// ---------------------------------------------------------------------------
// Output, batched over branches (y=b): beta = softmax(wsum[b*2..]/T);
// s = b0*meta0+b1*meta1; out = s@foW + fob
// ---------------------------------------------------------------------------
__global__ __launch_bounds__(256) void out_kernel(
    const u16* __restrict__ metab4, const float* __restrict__ wsum4,
    const u16* __restrict__ foWb, const float* __restrict__ fob,
    float* __restrict__ out)
{
    __shared__ short Bs[64 * 264];
    int b = blockIdx.y;
    int tid = threadIdx.x, wv = tid >> 6, l = tid & 63, q = l >> 4, c = l & 15;
    float w0 = wsum4[b * 2] * (1.f / TT), w1 = wsum4[b * 2 + 1] * (1.f / TT);
    float mxv = fmaxf(w0, w1);
    float e0 = __expf(w0 - mxv), e1 = __expf(w1 - mxv);
    float inv = 1.f / (e0 + e1);
    float b0 = e0 * inv, b1 = e1 * inv;
    const u16* W = foWb + b * 16384;
    short8 bv[8];
#pragma unroll
    for (int j = 0; j < 8; ++j)
        bv[j] = *(const short8*)&W[(tid + 256 * j) * 8];
    int rbase = blockIdx.x * 64;
    int row = rbase + wv * 16 + c;
    bool ok = row < TT;
    const u16* Ap0 = metab4 + (size_t)(b * 2) * TT * 256 + (size_t)row * 256 + q * 8;
    const u16* Ap1 = Ap0 + (size_t)TT * 256;
    short8 af[8];
#pragma unroll
    for (int half = 0; half < 2; ++half) {
        union { short8 s8; uint4 u; } ua[4], uc[4];
#pragma unroll
        for (int s = 0; s < 4; ++s) {
            int ss = half * 4 + s;
            ua[s].s8 = ok ? *(const short8*)(Ap0 + 32 * ss) : (short8)(short)0;
            uc[s].s8 = ok ? *(const short8*)(Ap1 + 32 * ss) : (short8)(short)0;
        }
        if (half == 0) {
#pragma unroll
            for (int j = 0; j < 8; ++j) {
                int e = tid + 256 * j, r = e >> 5, kc = (e & 31) * 8;
                *(short8*)&Bs[r * 264 + kc] = bv[j];
            }
        }
#pragma unroll
        for (int s = 0; s < 4; ++s) {
            float4 a0 = up4(ua[s].u.x, ua[s].u.y), a1 = up4(ua[s].u.z, ua[s].u.w);
            float4 c0 = up4(uc[s].u.x, uc[s].u.y), c1 = up4(uc[s].u.z, uc[s].u.w);
            float4 v0, v1;
            v0.x = b0 * a0.x + b1 * c0.x; v0.y = b0 * a0.y + b1 * c0.y;
            v0.z = b0 * a0.z + b1 * c0.z; v0.w = b0 * a0.w + b1 * c0.w;
            v1.x = b0 * a1.x + b1 * c1.x; v1.y = b0 * a1.y + b1 * c1.y;
            v1.z = b0 * a1.z + b1 * c1.z; v1.w = b0 * a1.w + b1 * c1.w;
            af[half * 4 + s] = cvt8(v0, v1);
        }
    }
    __syncthreads();
    f32x4 acc[4];
#pragma unroll
    for (int i = 0; i < 4; ++i) acc[i] = (f32x4){0.f, 0.f, 0.f, 0.f};
#pragma unroll
    for (int s = 0; s < 8; ++s)
#pragma unroll
        for (int t4 = 0; t4 < 4; ++t4)
            acc[t4] = MFMA16(af[s],
                *(const short8*)&Bs[(t4 * 16 + c) * 264 + q * 8 + 32 * s], acc[t4]);
    int grl = rbase + wv * 16 + q * 4;
#pragma unroll
    for (int t4 = 0; t4 < 4; ++t4) {
        int col = t4 * 16 + c;
        float bvv = fob[b * 64 + col];
#pragma unroll
        for (int reg = 0; reg < 4; ++reg) {
            int gr = grl + reg;
            if (gr < TT)
                out[(size_t)b * TT * 64 + (size_t)gr * 64 + col] = acc[t4][reg] + bvv;
        }
    }
}

// ---------------------------------------------------------------------------
extern "C" void kernel_launch(void* const* d_in, const int* in_sizes, int n_in,
                              void* d_out, int out_size, void* d_ws, size_t ws_size,
                              hipStream_t stream)
{
    const float* f0    = (const float*)d_in[0];
    const float* f1    = (const float*)d_in[1];
    const float* fcW   = (const float*)d_in[2];
    const float* fcb   = (const float*)d_in[3];
    const float* gatW  = (const float*)d_in[4];
    const float* al    = (const float*)d_in[5];
    const float* ar    = (const float*)d_in[6];
    const float* semW  = (const float*)d_in[7];
    const float* semb  = (const float*)d_in[8];
    const float* semq  = (const float*)d_in[9];
    const float* foW   = (const float*)d_in[10];
    const float* fob   = (const float*)d_in[11];
    const int* type_idx = (const int*)d_in[12];
    const int* node_idx = (const int*)d_in[13];
    const int* edge_src = (const int*)d_in[14];
    const int* edge_dst = (const int*)d_in[15];
    const int* tgt_idx  = (const int*)d_in[16];
    float* out = (float*)d_out;

    char* ws = (char*)d_ws;
    size_t off = 0;
    auto alloc = [&](size_t bytes) -> void* {
        void* p = ws + off;
        off = (off + bytes + 255) & ~(size_t)255;
        return p;
    };
    u16*   tbf         = (u16*)alloc((size_t)NT * 64 * 2);
    u16*   zb          = (u16*)alloc((size_t)NPG * 256 * 2);
    float* el          = (float*)alloc((size_t)NPG * 4 * 4);
    float* er          = (float*)alloc((size_t)NPG * 4 * 4);
    u16*   metab4      = (u16*)alloc((size_t)4 * TT * 256 * 2);
    float* wsum4       = (float*)alloc(64);
    u16*   fcWb        = (u16*)alloc(32768 * 2);
    u16*   gatWb       = (u16*)alloc(65536 * 2);
    u16*   semWb       = (u16*)alloc(131072 * 2);
    u16*   foWb        = (u16*)alloc(32768 * 2);
    int*   deg4        = (int*)alloc((size_t)4 * NPG * 4);
    int*   tflag4      = (int*)alloc((size_t)4 * NPG * 4);
    int*   offsets4    = (int*)alloc((size_t)4 * (NPG + 1) * 4);
    int*   cursor4     = (int*)alloc((size_t)4 * NPG * 4);
    int*   perm4       = (int*)alloc((size_t)4 * EG * 4);
    int*   part4       = (int*)alloc((size_t)4 * NPB * 4);
    int*   pref4       = (int*)alloc((size_t)4 * NPB * 4);

    const int eblocks = (EG + 255) / 256;
    const int tblocks = (TT + 255) / 256;

    prep_kernel<<<512, 256, 0, stream>>>(fcW, gatW, semW, foW,
                                         fcWb, gatWb, semWb, foWb);

    // --- batched target-only CSR build for all 4 graphs ---
    hipMemsetAsync(deg4, 0, (size_t)4 * NPG * 4, stream);
    hipMemsetAsync(tflag4, 0, (size_t)4 * NPG * 4, stream);
    hipMemsetAsync(wsum4, 0, 16, stream);
    mark_kernel<<<dim3(tblocks, 4), 256, 0, stream>>>(tgt_idx, tflag4);
    count4_kernel<<<dim3(eblocks, 4), 256, 0, stream>>>(edge_dst, tflag4, deg4);
    partial4_kernel<<<dim3(NPB, 4), 256, 0, stream>>>(deg4, part4);
    scanp_kernel<<<dim3(1, 4), 256, 0, stream>>>(part4, pref4, offsets4);
    distribute_kernel<<<dim3(NPB, 4), 256, 0, stream>>>(deg4, pref4, offsets4,
                                                        cursor4);
    scatter4_kernel<<<dim3(eblocks, 4), 256, 0, stream>>>(edge_dst, edge_src,
                                                          tflag4, cursor4, perm4);

    fc_kernel<<<dim3(782, 2), 256, 0, stream>>>(f0, f1, fcWb, fcb, type_idx, tbf);
    for (int g = 0; g < 4; ++g) {
        z_kernel<<<782, 256, 0, stream>>>(
            tbf, node_idx + (size_t)g * NPG, gatWb + (size_t)g * 16384,
            al + (size_t)g * 256, ar + (size_t)g * 256, zb, el, er);
        agg_kernel<<<TT, 256, 0, stream>>>(
            tgt_idx + (size_t)g * TT, offsets4 + (size_t)g * (NPG + 1),
            perm4 + (size_t)g * EG, el, er, zb, metab4 + (size_t)g * TT * 256);
    }
    sem_kernel<<<dim3(313, 4), 256, 0, stream>>>(metab4, semWb, semb, semq,
                                                 wsum4);
    out_kernel<<<dim3(313, 2), 256, 0, stream>>>(metab4, wsum4, foWb, fob, out);
}